// Round 11
// baseline (2532.408 us; speedup 1.0000x reference)
//
#include <hip/hip_runtime.h>
#include <hip/hip_cooperative_groups.h>
namespace cg = cooperative_groups;

#define NN   32768
#define NV   64
#define E0E  524288
#define HID  128
#define NL   4
#define NH   8
#define DH   16
#define SCALE 0.25f
#define PST  640   // P row stride: [q | k0 | v0 | k1 | v1]

__device__ __forceinline__ float gelu_f(float x) {
  return 0.5f * x * (1.0f + erff(x * 0.7071067811865475f));
}
__device__ __forceinline__ float sigmoid_f(float x) {
  return 1.0f / (1.0f + __expf(-x));
}

union SMem {
  struct { float As[64][36]; float Bs[32][132]; } g;   // 26112 B (max member)
  struct { float xs[4][HID]; float qq[4][HID]; float kk[4][HID]; float vv[4][HID];
           float oo[4][HID]; float att[NH][4][4]; float hb[HID]; float tb[64]; } f;
  int scan[256];
  float xr[HID];
};

struct MArgs {
  const float *x_op, *x_v;
  const int *ei0, *ei1;
  const float *Wk, *Wq, *Wv, *Wa, *bk, *bq, *bv, *ba, *skip, *a_rel, *m_rel, *p_rel;
  const float *win, *bin, *wout, *bout;
  const float *nw0, *nb0, *nw1, *nb1, *nw2, *nb2, *nw3, *nb3;
  const float *nw4, *nb4, *nw5, *nb5, *nw6, *nb6;
  const float *gw0, *gb0, *gw1, *gb1;
  float *P, *xop, *agg, *CW, *CB, *WqT, *WaT, *xv, *qv, *outsv, *part;
  int *rowptr0, *cur0, *col0, *rowptr1, *cur1, *col1;
  float *outp;
};

// ---------------- GEMM tile (r5 config: BM=64,BN=128,BK=32, 4x8 micro-tile) ----------------
__device__ __forceinline__ void gemm_tile(SMem& sm, int t,
    const float* __restrict__ A, const float* __restrict__ WT,
    const float* __restrict__ bias, float* __restrict__ out, int ldo, int cbase,
    int m0, int gelu_in, const float* __restrict__ skipv) {
  const int tx = t & 15, ty = t >> 4;
  const int smr = t >> 3;
  const int skk = (t & 7) * 4;
  const int bkr = t >> 5;
  const int bcc = (t & 31) * 4;
  float acc[4][8] = {};
  for (int kt = 0; kt < HID; kt += 32) {
    #pragma unroll
    for (int p = 0; p < 2; ++p) {
      int m = smr + p * 32;
      float4 av = *(const float4*)(A + (size_t)(m0 + m) * HID + kt + skk);
      if (gelu_in) { av.x = gelu_f(av.x); av.y = gelu_f(av.y); av.z = gelu_f(av.z); av.w = gelu_f(av.w); }
      *(float4*)&sm.g.As[m][skk] = av;
    }
    #pragma unroll
    for (int p = 0; p < 4; ++p) {
      int kk = bkr + p * 8;
      *(float4*)&sm.g.Bs[kk][bcc] = *(const float4*)(WT + (size_t)(kt + kk) * HID + bcc);
    }
    __syncthreads();
    #pragma unroll
    for (int k4 = 0; k4 < 32; k4 += 4) {
      float4 a4[4];
      #pragma unroll
      for (int r = 0; r < 4; ++r) a4[r] = *(const float4*)&sm.g.As[4 * ty + r][k4];
      #pragma unroll
      for (int j = 0; j < 4; ++j) {
        float4 b0 = *(const float4*)&sm.g.Bs[k4 + j][4 * tx];
        float4 b1 = *(const float4*)&sm.g.Bs[k4 + j][64 + 4 * tx];
        #pragma unroll
        for (int i = 0; i < 4; ++i) {
          float ai = ((const float*)&a4[i])[j];
          acc[i][0] += ai * b0.x; acc[i][1] += ai * b0.y;
          acc[i][2] += ai * b0.z; acc[i][3] += ai * b0.w;
          acc[i][4] += ai * b1.x; acc[i][5] += ai * b1.y;
          acc[i][6] += ai * b1.z; acc[i][7] += ai * b1.w;
        }
      }
    }
    __syncthreads();
  }
  float g = 0.f, gm1 = 0.f;
  if (skipv) { g = sigmoid_f(*skipv); gm1 = 1.0f - g; }
  #pragma unroll
  for (int i = 0; i < 4; ++i) {
    int m = m0 + 4 * ty + i;
    float* po = out + (size_t)m * ldo + cbase;
    #pragma unroll
    for (int hh = 0; hh < 2; ++hh) {
      int c = hh * 64 + 4 * tx;
      float4 bb = *(const float4*)(bias + c);
      float4 o;
      o.x = acc[i][hh * 4 + 0] + bb.x; o.y = acc[i][hh * 4 + 1] + bb.y;
      o.z = acc[i][hh * 4 + 2] + bb.z; o.w = acc[i][hh * 4 + 3] + bb.w;
      float* qp = po + c;
      if (skipv) {
        float4 xo = *(const float4*)qp;   // out aliases old-x (read-before-write)
        o.x = g * o.x + gm1 * xo.x; o.y = g * o.y + gm1 * xo.y;
        o.z = g * o.z + gm1 * xo.z; o.w = g * o.w + gm1 * xo.w;
      }
      *(float4*)qp = o;
    }
  }
}

// ---------------- the persistent cooperative kernel ----------------
__global__ __launch_bounds__(256, 4) void k_mega(MArgs a) {
  cg::grid_group grid = cg::this_grid();
  __shared__ SMem sm;
  const int t = threadIdx.x;
  const int G = gridDim.x;          // runtime grid (occupancy-clamped at launch)

  // ===== phase 0: zero + copies + weight combine (transposed) + weight transpose =====
  for (int u = blockIdx.x; u < 4256; u += G) {
    int b = u;
    if (b < 128) { int i = b * 256 + t; a.cur0[i] = 0; if (i < NV) a.cur1[i] = 0; continue; }
    b -= 128;
    if (b < 4096) { ((float4*)a.xop)[b * 256 + t] = ((const float4*)a.x_op)[b * 256 + t]; continue; }
    b -= 4096;
    if (b < 8) { ((float4*)a.xv)[b * 256 + t] = ((const float4*)a.x_v)[b * 256 + t]; continue; }
    b -= 8;
    if (b < 16) {
      int blk = b;
      int l = blk >> 2, mat = blk & 3;
      int rel = mat >> 1;
      int isK = ((mat & 1) == 0);
      const float* W  = (isK ? a.Wk : a.Wv) + (size_t)(l * 2) * HID * HID;
      const float* bb = (isK ? a.bk : a.bv) + (l * 2) * HID;
      const float* R  = (isK ? a.a_rel : a.m_rel) + (size_t)((l * 2 + rel) * NH) * DH * DH;
      float* cw = a.CW + (size_t)blk * HID * HID;
      float* cb = a.CB + blk * HID;
      for (int o = t; o < HID * HID; o += 256) {
        int j = o >> 7, c = o & 127;
        int h = j >> 4, e = j & 15;
        float sc = isK ? (a.p_rel[(l * 2 + rel) * NH + h] * SCALE) : 1.0f;
        float s = 0.f;
        #pragma unroll
        for (int d = 0; d < DH; ++d)
          s += W[(size_t)(h * DH + d) * HID + c] * R[h * 256 + d * 16 + e];
        cw[(size_t)c * HID + j] = s * sc;   // [k][n]
      }
      if (t < HID) {
        int j = t, h = j >> 4, e = j & 15;
        float sc = isK ? (a.p_rel[(l * 2 + rel) * NH + h] * SCALE) : 1.0f;
        float s = 0.f;
        #pragma unroll
        for (int d = 0; d < DH; ++d) s += bb[h * DH + d] * R[h * 256 + d * 16 + e];
        cb[j] = s * sc;
      }
      continue;
    }
    b -= 16;
    {
      int l = b >> 1;
      const float* src = ((b & 1) == 0 ? a.Wq : a.Wa) + (size_t)(l * 2) * HID * HID;
      float*       dst = ((b & 1) == 0 ? a.WqT : a.WaT) + (size_t)l * HID * HID;
      for (int o = t; o < HID * HID; o += 256) {
        int n = o >> 7, k = o & 127;
        dst[(size_t)k * HID + n] = src[o];
      }
    }
  }
  grid.sync();

  // ===== phase 1: histograms (4 edges/thread) =====
  {
    const int* dst0 = a.ei0 + E0E;
    const int* dst1 = a.ei1 + NN;
    for (int u = blockIdx.x; u < 544; u += G) {
      if (u < 512) {
        int base = u * 1024 + t;
        #pragma unroll
        for (int i = 0; i < 4; ++i) atomicAdd(&a.cur0[dst0[base + i * 256]], 1);
      } else {
        int base = (u - 512) * 1024 + t;
        #pragma unroll
        for (int i = 0; i < 4; ++i) atomicAdd(&a.cur1[dst1[base + i * 256]], 1);
      }
    }
  }
  grid.sync();

  // ===== phase 2: scans =====
  if (blockIdx.x == 0) {
    int base = t * 128;
    int s = 0;
    for (int i = 0; i < 128; ++i) s += a.cur0[base + i];
    sm.scan[t] = s;
    __syncthreads();
    for (int off = 1; off < 256; off <<= 1) {
      int v = (t >= off) ? sm.scan[t - off] : 0;
      __syncthreads();
      sm.scan[t] += v;
      __syncthreads();
    }
    int run = sm.scan[t] - s;
    for (int i = 0; i < 128; ++i) {
      int c = a.cur0[base + i];
      a.rowptr0[base + i] = run; a.cur0[base + i] = run; run += c;
    }
    if (t == 255) a.rowptr0[NN] = E0E;
  } else if (blockIdx.x == 1 && t < 64) {
    int v = a.cur1[t];
    int s = v;
    #pragma unroll
    for (int off = 1; off < 64; off <<= 1) {
      int u2 = __shfl_up(s, off);
      if (t >= off) s += u2;
    }
    int ex = s - v;
    a.rowptr1[t] = ex; a.cur1[t] = ex;
    if (t == 63) a.rowptr1[NV] = NN;
  }
  grid.sync();

  // ===== phase 3: scatters (4 edges/thread) =====
  {
    const int* src0 = a.ei0;       const int* dst0 = a.ei0 + E0E;
    const int* src1 = a.ei1;       const int* dst1 = a.ei1 + NN;
    for (int u = blockIdx.x; u < 544; u += G) {
      if (u < 512) {
        int base = u * 1024 + t;
        #pragma unroll
        for (int i = 0; i < 4; ++i) {
          int e = base + i * 256;
          int pos = atomicAdd(&a.cur0[dst0[e]], 1);
          a.col0[pos] = src0[e];
        }
      } else {
        int base = (u - 512) * 1024 + t;
        #pragma unroll
        for (int i = 0; i < 4; ++i) {
          int e = base + i * 256;
          int pos = atomicAdd(&a.cur1[dst1[e]], 1);
          a.col1[pos] = src1[e];
        }
      }
    }
  }
  grid.sync();

  // ===== layer loop =====
  for (int l = 0; l < NL; ++l) {
    // ---- proj: 2560 GEMM tiles (y = u>>9) + 64 rowproj units ----
    for (int u = blockIdx.x; u < 2624; u += G) {
      if (u < 2560) {
        int y = u >> 9;
        int m0 = (u & 511) * 64;
        const float* WT = (y == 0) ? (a.WqT + (size_t)l * HID * HID)
                                   : (a.CW + (size_t)(l * 4 + (y - 1)) * HID * HID);
        const float* bias = (y == 0) ? (a.bq + (l * 2 + 0) * HID)
                                     : (a.CB + (l * 4 + (y - 1)) * HID);
        gemm_tile(sm, t, a.xop, WT, bias, a.P, PST, y * HID, m0, 0, nullptr);
      } else {
        __syncthreads();                       // protect union vs previous unit
        int n = u - 2560;
        const float* rpW = a.Wq + (size_t)(l * 2 + 1) * HID * HID;
        const float* rpB = a.bq + (l * 2 + 1) * HID;
        if (t < HID) sm.xr[t] = a.xv[n * HID + t];
        __syncthreads();
        if (t < HID) {
          float s = rpB[t];
          const float4* wr = (const float4*)(rpW + (size_t)t * HID);
          const float4* xx = (const float4*)sm.xr;
          #pragma unroll 8
          for (int c = 0; c < HID / 4; ++c) {
            float4 w4 = wr[c], x4 = xx[c];
            s += x4.x * w4.x + x4.y * w4.y + x4.z * w4.z + x4.w * w4.w;
          }
          a.qv[n * HID + t] = s;
        }
        __syncthreads();
      }
    }
    grid.sync();

    // ---- edges: 4096 edge0 units (8 nodes each) + 512 edge1 units ----
    for (int u = blockIdx.x; u < 4608; u += G) {
      int lane = t & 63;
      if (u < 4096) {
        int wid = t >> 6;
        int half = lane >> 5;
        int l32 = lane & 31;
        int n = u * 8 + wid * 2 + half;
        int c4 = 4 * l32;
        float4 q = *(const float4*)(a.P + (size_t)n * PST + c4);
        const float* Pb = a.P + c4;
        int e0 = a.rowptr0[n], e1 = a.rowptr0[n + 1];
        float4 acc = make_float4(0.f, 0.f, 0.f, 0.f);
        float wsum = 0.f;
        int e = e0;
        for (; e + 8 <= e1; e += 8) {
          int off[8];
          #pragma unroll
          for (int v = 0; v < 8; ++v) off[v] = a.col0[e + v] * PST;
          float4 kx[8], vx[8];
          #pragma unroll
          for (int v = 0; v < 8; ++v) kx[v] = *(const float4*)(Pb + off[v] + 128);
          #pragma unroll
          for (int v = 0; v < 8; ++v) vx[v] = *(const float4*)(Pb + off[v] + 256);
          float p[8];
          #pragma unroll
          for (int v = 0; v < 8; ++v)
            p[v] = q.x * kx[v].x + q.y * kx[v].y + q.z * kx[v].z + q.w * kx[v].w;
          #pragma unroll
          for (int v = 0; v < 8; ++v) { p[v] += __shfl_xor(p[v], 1); p[v] += __shfl_xor(p[v], 2); }
          #pragma unroll
          for (int v = 0; v < 8; ++v) {
            float w = __expf(p[v]);
            wsum += w;
            acc.x += w * vx[v].x; acc.y += w * vx[v].y;
            acc.z += w * vx[v].z; acc.w += w * vx[v].w;
          }
        }
        for (; e < e1; ++e) {
          int off = a.col0[e] * PST;
          float4 kx = *(const float4*)(Pb + off + 128);
          float p = q.x * kx.x + q.y * kx.y + q.z * kx.z + q.w * kx.w;
          p += __shfl_xor(p, 1); p += __shfl_xor(p, 2);
          float w = __expf(p);
          float4 vx = *(const float4*)(Pb + off + 256);
          wsum += w;
          acc.x += w * vx.x; acc.y += w * vx.y; acc.z += w * vx.z; acc.w += w * vx.w;
        }
        float inv = 1.0f / (wsum + 1e-16f);
        acc.x *= inv; acc.y *= inv; acc.z *= inv; acc.w *= inv;
        *(float4*)(a.agg + (size_t)n * HID + c4) = acc;
      } else {
        int b2 = u - 4096;
        int g2 = b2 >> 3, ch = b2 & 7;
        int w = t >> 6;
        int slot = ch * 4 + w;
        float2 q = *(const float2*)(a.qv + g2 * HID + 2 * lane);
        int e0 = a.rowptr1[g2], e1 = a.rowptr1[g2 + 1];
        int tot = e1 - e0;
        int len = (tot + 31) >> 5;
        int s0 = e0 + slot * len;
        int s1 = s0 + len; if (s1 > e1) s1 = e1;
        float acc0 = 0.f, acc1 = 0.f, wsum = 0.f;
        int e = s0;
        for (; e + 4 <= s1; e += 4) {
          const float* ra = a.P + (size_t)a.col1[e]     * PST + 2 * lane;
          const float* rb = a.P + (size_t)a.col1[e + 1] * PST + 2 * lane;
          const float* rc = a.P + (size_t)a.col1[e + 2] * PST + 2 * lane;
          const float* rd = a.P + (size_t)a.col1[e + 3] * PST + 2 * lane;
          float2 ka = *(const float2*)(ra + 384);
          float2 kb = *(const float2*)(rb + 384);
          float2 kc = *(const float2*)(rc + 384);
          float2 kd = *(const float2*)(rd + 384);
          float2 va = *(const float2*)(ra + 512);
          float2 vb = *(const float2*)(rb + 512);
          float2 vc = *(const float2*)(rc + 512);
          float2 vd = *(const float2*)(rd + 512);
          float pa = q.x * ka.x + q.y * ka.y;
          float pb = q.x * kb.x + q.y * kb.y;
          float pc = q.x * kc.x + q.y * kc.y;
          float pd = q.x * kd.x + q.y * kd.y;
          pa += __shfl_xor(pa, 1); pb += __shfl_xor(pb, 1); pc += __shfl_xor(pc, 1); pd += __shfl_xor(pd, 1);
          pa += __shfl_xor(pa, 2); pb += __shfl_xor(pb, 2); pc += __shfl_xor(pc, 2); pd += __shfl_xor(pd, 2);
          pa += __shfl_xor(pa, 4); pb += __shfl_xor(pb, 4); pc += __shfl_xor(pc, 4); pd += __shfl_xor(pd, 4);
          float wa = __expf(pa), wb = __expf(pb), wc = __expf(pc), wd = __expf(pd);
          wsum += (wa + wb) + (wc + wd);
          acc0 += wa * va.x + wb * vb.x + wc * vc.x + wd * vd.x;
          acc1 += wa * va.y + wb * vb.y + wc * vc.y + wd * vd.y;
        }
        for (; e < s1; ++e) {
          const float* row = a.P + (size_t)a.col1[e] * PST + 2 * lane;
          float2 kv = *(const float2*)(row + 384);
          float p = q.x * kv.x + q.y * kv.y;
          p += __shfl_xor(p, 1); p += __shfl_xor(p, 2); p += __shfl_xor(p, 4);
          float ww = __expf(p);
          float2 vv = *(const float2*)(row + 512);
          wsum += ww; acc0 += ww * vv.x; acc1 += ww * vv.y;
        }
        float* pp = a.part + (size_t)(g2 * 32 + slot) * 192;
        pp[lane] = acc0; pp[64 + lane] = acc1; pp[128 + lane] = wsum;
      }
    }
    grid.sync();

    // ---- post: 512 out-GEMM tiles + 64 vnode tails ----
    for (int u = blockIdx.x; u < 576; u += G) {
      if (u < 512) {
        gemm_tile(sm, t, a.agg, a.WaT + (size_t)l * HID * HID,
                  a.ba + (l * 2 + 0) * HID, a.xop, HID, 0, u * 64, 1,
                  a.skip + l * 2 + 0);
      } else {
        __syncthreads();
        int v = u - 512;
        const float* Wa1 = a.Wa + (size_t)(l * 2 + 1) * HID * HID;
        const float* ba1 = a.ba + (l * 2 + 1) * HID;
        if (t < 64) {
          float a0 = 0.f, a1 = 0.f, ws2 = 0.f;
          for (int s = 0; s < 32; ++s) {
            const float* p = a.part + (size_t)(v * 32 + s) * 192;
            a0 += p[t]; a1 += p[64 + t]; ws2 += p[128 + t];
          }
          float inv = 1.0f / (ws2 + 1e-16f);
          sm.xr[2 * t]     = gelu_f(a0 * inv);
          sm.xr[2 * t + 1] = gelu_f(a1 * inv);
        }
        __syncthreads();
        if (t < HID) {
          float s = ba1[t];
          const float4* wr = (const float4*)(Wa1 + (size_t)t * HID);
          const float4* xx = (const float4*)sm.xr;
          #pragma unroll 8
          for (int c = 0; c < HID / 4; ++c) {
            float4 w4 = wr[c], x4 = xx[c];
            s += x4.x * w4.x + x4.y * w4.y + x4.z * w4.z + x4.w * w4.w;
          }
          float gg = sigmoid_f(a.skip[l * 2 + 1]);
          float nv2 = gg * s + (1.f - gg) * a.xv[v * HID + t];
          a.xv[v * HID + t] = nv2;
          a.outsv[(size_t)l * NV * HID + v * HID + t] = nv2;
        }
        __syncthreads();
      }
    }
    grid.sync();
  }

  // ===== final: JK attention + MLPs, one unit per virtual node =====
  for (int u = blockIdx.x; u < NV; u += G) {
    __syncthreads();
    int b = u;
    if (t < 128) for (int l = 0; l < 4; ++l) sm.f.xs[l][t] = a.outsv[(size_t)(l * NV + b) * HID + t];
    __syncthreads();
    if (t < 128) {
      for (int l = 0; l < 4; ++l) {
        float sq = a.bin[t], sk = a.bin[t + 128], sv = a.bin[t + 256];
        const float* wq = a.win + (size_t)t * HID;
        const float* wk = a.win + (size_t)(t + 128) * HID;
        const float* wv = a.win + (size_t)(t + 256) * HID;
        for (int c = 0; c < HID; ++c) {
          float x = sm.f.xs[l][c];
          sq += x * wq[c]; sk += x * wk[c]; sv += x * wv[c];
        }
        sm.f.qq[l][t] = sq; sm.f.kk[l][t] = sk; sm.f.vv[l][t] = sv;
      }
    }
    __syncthreads();
    if (t < 128) {
      int h = t >> 4, ql = (t >> 2) & 3, kl = t & 3;
      float s = 0.f;
      #pragma unroll
      for (int d = 0; d < DH; ++d) s += sm.f.qq[ql][h * DH + d] * sm.f.kk[kl][h * DH + d];
      sm.f.att[h][ql][kl] = s * SCALE;
    }
    __syncthreads();
    if (t < 32) {
      int h = t >> 2, ql = t & 3;
      float m = sm.f.att[h][ql][0];
      for (int k2 = 1; k2 < 4; ++k2) m = fmaxf(m, sm.f.att[h][ql][k2]);
      float e[4], s = 0.f;
      for (int k2 = 0; k2 < 4; ++k2) { e[k2] = __expf(sm.f.att[h][ql][k2] - m); s += e[k2]; }
      for (int k2 = 0; k2 < 4; ++k2) sm.f.att[h][ql][k2] = e[k2] / s;
    }
    __syncthreads();
    if (t < 128) {
      int h = t >> 4;
      #pragma unroll
      for (int ql = 0; ql < 4; ++ql) {
        float s = 0.f;
        #pragma unroll
        for (int kl = 0; kl < 4; ++kl) s += sm.f.att[h][ql][kl] * sm.f.vv[kl][t];
        sm.f.oo[ql][t] = s;
      }
    }
    __syncthreads();
    if (t < 128) {
      float s = 0.f;
      const float* wr = a.wout + (size_t)t * HID;
      for (int l = 0; l < 4; ++l) {
        float ss = a.bout[t];
        for (int c = 0; c < HID; ++c) ss += sm.f.oo[l][c] * wr[c];
        s += ss;
      }
      sm.f.hb[t] = s;
    }
    __syncthreads();
    if (t < 64) { float s = a.nb0[t]; const float* wr = a.nw0 + t * 128; for (int c = 0; c < 128; ++c) s += sm.f.hb[c] * wr[c]; sm.f.tb[t] = gelu_f(s); }
    __syncthreads();
    if (t < 32) { float s = a.nb1[t]; const float* wr = a.nw1 + t * 64;  for (int c = 0; c < 64;  ++c) s += sm.f.tb[c] * wr[c]; sm.f.hb[t] = gelu_f(s); }
    __syncthreads();
    if (t < 16) { float s = a.nb2[t]; const float* wr = a.nw2 + t * 32;  for (int c = 0; c < 32;  ++c) s += sm.f.hb[c] * wr[c]; sm.f.tb[t] = gelu_f(s); }
    __syncthreads();
    if (t < 8)  { float s = a.nb3[t]; const float* wr = a.nw3 + t * 16;  for (int c = 0; c < 16;  ++c) s += sm.f.tb[c] * wr[c]; sm.f.hb[t] = gelu_f(s); }
    __syncthreads();
    if (t < 4)  { float s = a.nb4[t]; const float* wr = a.nw4 + t * 8;   for (int c = 0; c < 8;   ++c) s += sm.f.hb[c] * wr[c]; sm.f.tb[t] = gelu_f(s); }
    __syncthreads();
    if (t < 2)  { float s = a.nb5[t]; const float* wr = a.nw5 + t * 4;   for (int c = 0; c < 4;   ++c) s += sm.f.tb[c] * wr[c]; sm.f.hb[t] = gelu_f(s); }
    __syncthreads();
    if (t == 0) {
      float s = sm.f.hb[0] * a.nw6[0] + sm.f.hb[1] * a.nw6[1] + a.nb6[0];
      float g0 = gelu_f(s * a.gw0[0] + a.gb0[0]);
      float g1 = gelu_f(s * a.gw0[1] + a.gb0[1]);
      a.outp[b] = g0 * a.gw1[0] + g1 * a.gw1[1] + a.gb1[0];
    }
    __syncthreads();
  }
}

// ================= host =======================================================================
extern "C" void kernel_launch(void* const* d_in, const int* in_sizes, int n_in,
                              void* d_out, int out_size, void* d_ws, size_t ws_size,
                              hipStream_t stream) {
  (void)in_sizes; (void)n_in; (void)out_size; (void)ws_size;
  char* wsp = (char*)d_ws;
  size_t off = 0;
  auto alloc = [&](size_t bytes) -> void* {
    void* p = wsp + off;
    off += (bytes + 255) & ~(size_t)255;
    return p;
  };
  MArgs a;
  a.x_op = (const float*)d_in[0];
  a.x_v  = (const float*)d_in[1];
  a.ei0  = (const int*)d_in[2];
  a.ei1  = (const int*)d_in[3];
  a.Wk   = (const float*)d_in[4];
  a.Wq   = (const float*)d_in[5];
  a.Wv   = (const float*)d_in[6];
  a.Wa   = (const float*)d_in[7];
  a.bk   = (const float*)d_in[8];
  a.bq   = (const float*)d_in[9];
  a.bv   = (const float*)d_in[10];
  a.ba   = (const float*)d_in[11];
  a.skip = (const float*)d_in[12];
  a.a_rel = (const float*)d_in[13];
  a.m_rel = (const float*)d_in[14];
  a.p_rel = (const float*)d_in[15];
  a.win  = (const float*)d_in[16]; a.bin  = (const float*)d_in[17];
  a.wout = (const float*)d_in[18]; a.bout = (const float*)d_in[19];
  a.nw0 = (const float*)d_in[20]; a.nb0 = (const float*)d_in[21];
  a.nw1 = (const float*)d_in[22]; a.nb1 = (const float*)d_in[23];
  a.nw2 = (const float*)d_in[24]; a.nb2 = (const float*)d_in[25];
  a.nw3 = (const float*)d_in[26]; a.nb3 = (const float*)d_in[27];
  a.nw4 = (const float*)d_in[28]; a.nb4 = (const float*)d_in[29];
  a.nw5 = (const float*)d_in[30]; a.nb5 = (const float*)d_in[31];
  a.nw6 = (const float*)d_in[32]; a.nb6 = (const float*)d_in[33];
  a.gw0 = (const float*)d_in[34]; a.gb0 = (const float*)d_in[35];
  a.gw1 = (const float*)d_in[36]; a.gb1 = (const float*)d_in[37];

  a.P     = (float*)alloc((size_t)NN * PST * 4);
  a.xop   = (float*)alloc((size_t)NN * HID * 4);
  a.agg   = (float*)alloc((size_t)NN * HID * 4);
  a.CW    = (float*)alloc((size_t)16 * HID * HID * 4);
  a.CB    = (float*)alloc((size_t)16 * HID * 4);
  a.WqT   = (float*)alloc((size_t)NL * HID * HID * 4);
  a.WaT   = (float*)alloc((size_t)NL * HID * HID * 4);
  a.xv    = (float*)alloc((size_t)NV * HID * 4);
  a.qv    = (float*)alloc((size_t)NV * HID * 4);
  a.outsv = (float*)alloc((size_t)NL * NV * HID * 4);
  a.part  = (float*)alloc((size_t)NV * 32 * 192 * 4);
  a.rowptr0 = (int*)alloc((size_t)(NN + 1) * 4);
  a.cur0    = (int*)alloc((size_t)NN * 4);
  a.col0    = (int*)alloc((size_t)E0E * 4);
  a.rowptr1 = (int*)alloc((size_t)(NV + 1) * 4);
  a.cur1    = (int*)alloc((size_t)NV * 4);
  a.col1    = (int*)alloc((size_t)NN * 4);
  a.outp = (float*)d_out;

  // Query actual co-residency instead of assuming 4 blocks/CU (r10 failed:
  // hard-coded 1024 blocks exceeded the runtime's cooperative-launch limit).
  int perCU = 0;
  hipOccupancyMaxActiveBlocksPerMultiprocessor(&perCU, (const void*)k_mega, 256, 0);
  if (perCU < 1) perCU = 1;
  int grid = perCU * 256;           // 256 CUs on MI355X
  if (grid > 1024) grid = 1024;     // no benefit beyond 4/CU; caps sync cost
  if (grid < 2) grid = 2;           // scan phase uses blocks 0 and 1

  void* params[] = { &a };
  hipLaunchCooperativeKernel((const void*)k_mega, dim3(grid), dim3(256), params, 0, stream);
}

// Round 12
// 1030.431 us; speedup vs baseline: 2.4576x; 2.4576x over previous
//
#include <hip/hip_runtime.h>

#define NN   32768
#define NV   64
#define E0E  524288
#define HID  128
#define NL   4
#define NH   8
#define DH   16
#define SCALE 0.25f
#define PST  640   // P row stride: [q | k0 | v0 | k1 | v1]

__device__ __forceinline__ float gelu_f(float x) {
  return 0.5f * x * (1.0f + erff(x * 0.7071067811865475f));
}
__device__ __forceinline__ float sigmoid_f(float x) {
  return 1.0f / (1.0f + __expf(-x));
}

// ---------------- GEMM tile (r5 config: BM=64,BN=128,BK=32, 4x8 micro-tile) ----------------
// skipv/skipsrc: if skipv != null, out = g*val + (1-g)*skipsrc (skipsrc may differ from out).
__device__ __forceinline__ void gemm_tile(float As[64][36], float Bs[32][132], int t,
    const float* __restrict__ A, const float* __restrict__ WT,
    const float* __restrict__ bias, float* __restrict__ out, int ldo, int cbase,
    int m0, int gelu_in, const float* __restrict__ skipv, const float* __restrict__ skipsrc) {
  const int tx = t & 15, ty = t >> 4;
  const int smr = t >> 3;
  const int skk = (t & 7) * 4;
  const int bkr = t >> 5;
  const int bcc = (t & 31) * 4;
  float acc[4][8] = {};
  for (int kt = 0; kt < HID; kt += 32) {
    #pragma unroll
    for (int p = 0; p < 2; ++p) {
      int m = smr + p * 32;
      float4 av = *(const float4*)(A + (size_t)(m0 + m) * HID + kt + skk);
      if (gelu_in) { av.x = gelu_f(av.x); av.y = gelu_f(av.y); av.z = gelu_f(av.z); av.w = gelu_f(av.w); }
      *(float4*)&As[m][skk] = av;
    }
    #pragma unroll
    for (int p = 0; p < 4; ++p) {
      int kk = bkr + p * 8;
      *(float4*)&Bs[kk][bcc] = *(const float4*)(WT + (size_t)(kt + kk) * HID + bcc);
    }
    __syncthreads();
    #pragma unroll
    for (int k4 = 0; k4 < 32; k4 += 4) {
      float4 a4[4];
      #pragma unroll
      for (int r = 0; r < 4; ++r) a4[r] = *(const float4*)&As[4 * ty + r][k4];
      #pragma unroll
      for (int j = 0; j < 4; ++j) {
        float4 b0 = *(const float4*)&Bs[k4 + j][4 * tx];
        float4 b1 = *(const float4*)&Bs[k4 + j][64 + 4 * tx];
        #pragma unroll
        for (int i = 0; i < 4; ++i) {
          float ai = ((const float*)&a4[i])[j];
          acc[i][0] += ai * b0.x; acc[i][1] += ai * b0.y;
          acc[i][2] += ai * b0.z; acc[i][3] += ai * b0.w;
          acc[i][4] += ai * b1.x; acc[i][5] += ai * b1.y;
          acc[i][6] += ai * b1.z; acc[i][7] += ai * b1.w;
        }
      }
    }
    __syncthreads();
  }
  float g = 0.f, gm1 = 0.f;
  if (skipv) { g = sigmoid_f(*skipv); gm1 = 1.0f - g; }
  #pragma unroll
  for (int i = 0; i < 4; ++i) {
    int m = m0 + 4 * ty + i;
    float* po = out + (size_t)m * ldo + cbase;
    #pragma unroll
    for (int hh = 0; hh < 2; ++hh) {
      int c = hh * 64 + 4 * tx;
      float4 bb = *(const float4*)(bias + c);
      float4 o;
      o.x = acc[i][hh * 4 + 0] + bb.x; o.y = acc[i][hh * 4 + 1] + bb.y;
      o.z = acc[i][hh * 4 + 2] + bb.z; o.w = acc[i][hh * 4 + 3] + bb.w;
      if (skipv) {
        float4 xo = *(const float4*)(skipsrc + (size_t)m * ldo + cbase + c);
        o.x = g * o.x + gm1 * xo.x; o.y = g * o.y + gm1 * xo.y;
        o.z = g * o.z + gm1 * xo.z; o.w = g * o.w + gm1 * xo.w;
      }
      *(float4*)(po + c) = o;
    }
  }
}

// ================= setup: zero + weight-combine (transposed) + weight-transpose ===============
// blocks: [0,128) zero cur | [128,144) combine | [144,152) transp
__global__ __launch_bounds__(256) void k_setup(
    int* __restrict__ cur0, int* __restrict__ cur1,
    const float* __restrict__ Wk, const float* __restrict__ Wv,
    const float* __restrict__ bk, const float* __restrict__ bv,
    const float* __restrict__ a_rel, const float* __restrict__ m_rel,
    const float* __restrict__ p_rel,
    float* __restrict__ CW, float* __restrict__ CB,
    const float* __restrict__ Wq, const float* __restrict__ Wa,
    float* __restrict__ WqT, float* __restrict__ WaT) {
  int b = blockIdx.x, t = threadIdx.x;
  if (b < 128) { int i = b * 256 + t; cur0[i] = 0; if (i < NV) cur1[i] = 0; return; }
  b -= 128;
  if (b < 16) {
    int blk = b;
    int l = blk >> 2, mat = blk & 3;
    int rel = mat >> 1;
    int isK = ((mat & 1) == 0);
    const float* W  = (isK ? Wk : Wv) + (size_t)(l * 2) * HID * HID;
    const float* bb = (isK ? bk : bv) + (l * 2) * HID;
    const float* R  = (isK ? a_rel : m_rel) + (size_t)((l * 2 + rel) * NH) * DH * DH;
    float* cw = CW + (size_t)blk * HID * HID;
    float* cb = CB + blk * HID;
    for (int o = t; o < HID * HID; o += 256) {
      int j = o >> 7, c = o & 127;
      int h = j >> 4, e = j & 15;
      float sc = isK ? (p_rel[(l * 2 + rel) * NH + h] * SCALE) : 1.0f;
      float s = 0.f;
      #pragma unroll
      for (int d = 0; d < DH; ++d)
        s += W[(size_t)(h * DH + d) * HID + c] * R[h * 256 + d * 16 + e];
      cw[(size_t)c * HID + j] = s * sc;   // [k][n]
    }
    if (t < HID) {
      int j = t, h = j >> 4, e = j & 15;
      float sc = isK ? (p_rel[(l * 2 + rel) * NH + h] * SCALE) : 1.0f;
      float s = 0.f;
      #pragma unroll
      for (int d = 0; d < DH; ++d) s += bb[h * DH + d] * R[h * 256 + d * 16 + e];
      cb[j] = s * sc;
    }
    return;
  }
  b -= 16;
  {
    int l = b >> 1;
    const float* src = ((b & 1) == 0 ? Wq : Wa) + (size_t)(l * 2) * HID * HID;
    float*       dst = ((b & 1) == 0 ? WqT : WaT) + (size_t)l * HID * HID;
    for (int o = t; o < HID * HID; o += 256) {
      int n = o >> 7, k = o & 127;
      dst[(size_t)k * HID + n] = src[o];
    }
  }
}

// ================= histograms (4 edges/thread) ================================================
__global__ __launch_bounds__(256) void k_hist2(const int* __restrict__ dst0,
                                               const int* __restrict__ dst1,
                                               int* __restrict__ cur0, int* __restrict__ cur1) {
  int b = blockIdx.x, t = threadIdx.x;
  if (b < E0E / 1024) {
    int base = b * 1024 + t;
    #pragma unroll
    for (int i = 0; i < 4; ++i) atomicAdd(&cur0[dst0[base + i * 256]], 1);
  } else {
    int base = (b - E0E / 1024) * 1024 + t;
    #pragma unroll
    for (int i = 0; i < 4; ++i) atomicAdd(&cur1[dst1[base + i * 256]], 1);
  }
}

// ================= scans ======================================================================
__global__ __launch_bounds__(1024) void k_scan2(int* __restrict__ cnt0, int* __restrict__ rp0,
                                                int* __restrict__ cnt1, int* __restrict__ rp1) {
  __shared__ int sd[1024];
  int t = threadIdx.x;
  if (blockIdx.x == 0) {
    int loc[32];
    int base = t * 32, s = 0;
    #pragma unroll
    for (int i = 0; i < 32; ++i) { loc[i] = cnt0[base + i]; s += loc[i]; }
    sd[t] = s;
    __syncthreads();
    for (int off = 1; off < 1024; off <<= 1) {
      int v = (t >= off) ? sd[t - off] : 0;
      __syncthreads();
      sd[t] += v;
      __syncthreads();
    }
    int run = sd[t] - s;
    #pragma unroll
    for (int i = 0; i < 32; ++i) { rp0[base + i] = run; cnt0[base + i] = run; run += loc[i]; }
    if (t == 1023) rp0[NN] = E0E;
  } else if (t < 64) {
    int v = cnt1[t];
    int s = v;
    #pragma unroll
    for (int off = 1; off < 64; off <<= 1) {
      int u = __shfl_up(s, off);
      if (t >= off) s += u;
    }
    int ex = s - v;
    rp1[t] = ex; cnt1[t] = ex;
    if (t == 63) rp1[NV] = NN;
  }
}

// ================= scatters (4 edges/thread) ==================================================
__global__ __launch_bounds__(256) void k_scat2(const int* __restrict__ src0,
                                               const int* __restrict__ dst0,
                                               int* __restrict__ cur0, int* __restrict__ col0,
                                               const int* __restrict__ src1,
                                               const int* __restrict__ dst1,
                                               int* __restrict__ cur1, int* __restrict__ col1) {
  int b = blockIdx.x, t = threadIdx.x;
  if (b < E0E / 1024) {
    int base = b * 1024 + t;
    #pragma unroll
    for (int i = 0; i < 4; ++i) {
      int e = base + i * 256;
      int pos = atomicAdd(&cur0[dst0[e]], 1);
      col0[pos] = src0[e];
    }
  } else {
    int base = (b - E0E / 1024) * 1024 + t;
    #pragma unroll
    for (int i = 0; i < 4; ++i) {
      int e = base + i * 256;
      int pos = atomicAdd(&cur1[dst1[e]], 1);
      col1[pos] = src1[e];
    }
  }
}

// ================= k_proj0: layer-0 projection (reads x_op input directly) ====================
struct WSet { const float* w[5]; const float* b[5]; };

__launch_bounds__(256)
__global__ void k_proj0(const float* __restrict__ A, WSet ws, float* __restrict__ P,
                        const float* __restrict__ rpW, const float* __restrict__ rpB,
                        const float* __restrict__ rpX, float* __restrict__ qvout) {
  __shared__ float As[64][36];
  __shared__ float Bs[32][132];
  const int t = threadIdx.x;
  if (blockIdx.y == 5) {           // rowproj: qv0 = x_v @ Wq[0,1]^T + bq
    __shared__ float xr[HID];
    int n = blockIdx.x;
    if (n >= NV) return;
    if (t < HID) xr[t] = rpX[n * HID + t];
    __syncthreads();
    if (t < HID) {
      float s = rpB[t];
      const float4* wr = (const float4*)(rpW + (size_t)t * HID);
      const float4* xx = (const float4*)xr;
      #pragma unroll 8
      for (int c = 0; c < HID / 4; ++c) {
        float4 w4 = wr[c], x4 = xx[c];
        s += x4.x * w4.x + x4.y * w4.y + x4.z * w4.z + x4.w * w4.w;
      }
      qvout[n * HID + t] = s;
    }
    return;
  }
  gemm_tile(As, Bs, t, A, ws.w[blockIdx.y], ws.b[blockIdx.y], P, PST,
            blockIdx.y * HID, blockIdx.x * 64, 0, nullptr, nullptr);
}

// ================= k_edges: edge0 (blocks < NN/4) + edge1 (NN/4 .. +512) — r8 best form =======
__launch_bounds__(256)
__global__ void k_edges(const float* __restrict__ P, const int* __restrict__ rowptr0,
                        const int* __restrict__ col0, float* __restrict__ agg,
                        const float* __restrict__ qv, const int* __restrict__ rowptr1,
                        const int* __restrict__ col1, float* __restrict__ part) {
  int lane = threadIdx.x & 63;
  if (blockIdx.x < NN / 4) {
    int n = blockIdx.x * 4 + (threadIdx.x >> 6);
    float2 q = *(const float2*)(P + (size_t)n * PST + 2 * lane);
    int e0 = rowptr0[n], e1 = rowptr0[n + 1];
    float acc0 = 0.f, acc1 = 0.f, wsum = 0.f;
    int e = e0;
    for (; e + 8 <= e1; e += 8) {
      const float* r[8];
      #pragma unroll
      for (int u = 0; u < 8; ++u) r[u] = P + (size_t)col0[e + u] * PST + 2 * lane;
      float2 kx[8], vx[8];
      #pragma unroll
      for (int u = 0; u < 8; ++u) kx[u] = *(const float2*)(r[u] + 128);
      #pragma unroll
      for (int u = 0; u < 8; ++u) vx[u] = *(const float2*)(r[u] + 256);
      float p[8];
      #pragma unroll
      for (int u = 0; u < 8; ++u) p[u] = q.x * kx[u].x + q.y * kx[u].y;
      #pragma unroll
      for (int u = 0; u < 8; ++u) {
        p[u] += __shfl_xor(p[u], 1); p[u] += __shfl_xor(p[u], 2); p[u] += __shfl_xor(p[u], 4);
      }
      #pragma unroll
      for (int u = 0; u < 8; ++u) {
        float w = __expf(p[u]);
        wsum += w; acc0 += w * vx[u].x; acc1 += w * vx[u].y;
      }
    }
    for (; e < e1; ++e) {
      const float* row = P + (size_t)col0[e] * PST + 2 * lane;
      float2 kv = *(const float2*)(row + 128);
      float p = q.x * kv.x + q.y * kv.y;
      p += __shfl_xor(p, 1); p += __shfl_xor(p, 2); p += __shfl_xor(p, 4);
      float w = __expf(p);
      float2 vv = *(const float2*)(row + 256);
      wsum += w; acc0 += w * vv.x; acc1 += w * vv.y;
    }
    float inv = 1.0f / (wsum + 1e-16f);
    *(float2*)(agg + (size_t)n * HID + 2 * lane) = make_float2(acc0 * inv, acc1 * inv);
  } else {
    int b2 = blockIdx.x - NN / 4;
    int g = b2 >> 3, ch = b2 & 7;
    int w = threadIdx.x >> 6;
    int slot = ch * 4 + w;
    float2 q = *(const float2*)(qv + g * HID + 2 * lane);
    int e0 = rowptr1[g], e1 = rowptr1[g + 1];
    int tot = e1 - e0;
    int len = (tot + 31) >> 5;
    int s0 = e0 + slot * len;
    int s1 = s0 + len; if (s1 > e1) s1 = e1;
    float acc0 = 0.f, acc1 = 0.f, wsum = 0.f;
    int e = s0;
    for (; e + 4 <= s1; e += 4) {
      const float* ra = P + (size_t)col1[e]     * PST + 2 * lane;
      const float* rb = P + (size_t)col1[e + 1] * PST + 2 * lane;
      const float* rc = P + (size_t)col1[e + 2] * PST + 2 * lane;
      const float* rd = P + (size_t)col1[e + 3] * PST + 2 * lane;
      float2 ka = *(const float2*)(ra + 384);
      float2 kb = *(const float2*)(rb + 384);
      float2 kc = *(const float2*)(rc + 384);
      float2 kd = *(const float2*)(rd + 384);
      float2 va = *(const float2*)(ra + 512);
      float2 vb = *(const float2*)(rb + 512);
      float2 vc = *(const float2*)(rc + 512);
      float2 vd = *(const float2*)(rd + 512);
      float pa = q.x * ka.x + q.y * ka.y;
      float pb = q.x * kb.x + q.y * kb.y;
      float pc = q.x * kc.x + q.y * kc.y;
      float pd = q.x * kd.x + q.y * kd.y;
      pa += __shfl_xor(pa, 1); pb += __shfl_xor(pb, 1); pc += __shfl_xor(pc, 1); pd += __shfl_xor(pd, 1);
      pa += __shfl_xor(pa, 2); pb += __shfl_xor(pb, 2); pc += __shfl_xor(pc, 2); pd += __shfl_xor(pd, 2);
      pa += __shfl_xor(pa, 4); pb += __shfl_xor(pb, 4); pc += __shfl_xor(pc, 4); pd += __shfl_xor(pd, 4);
      float wa = __expf(pa), wb = __expf(pb), wc = __expf(pc), wd = __expf(pd);
      wsum += (wa + wb) + (wc + wd);
      acc0 += wa * va.x + wb * vb.x + wc * vc.x + wd * vd.x;
      acc1 += wa * va.y + wb * vb.y + wc * vc.y + wd * vd.y;
    }
    for (; e < s1; ++e) {
      const float* row = P + (size_t)col1[e] * PST + 2 * lane;
      float2 kv = *(const float2*)(row + 384);
      float p = q.x * kv.x + q.y * kv.y;
      p += __shfl_xor(p, 1); p += __shfl_xor(p, 2); p += __shfl_xor(p, 4);
      float ww = __expf(p);
      float2 vv = *(const float2*)(row + 512);
      wsum += ww; acc0 += ww * vv.x; acc1 += ww * vv.y;
    }
    float* pp = part + (size_t)(g * 32 + slot) * 192;
    pp[lane] = acc0; pp[64 + lane] = acc1; pp[128 + lane] = wsum;
  }
}

// ================= k_fused: post(l) then proj(l+1) for same rows, in-block ====================
struct FArgs {
  const float *agg, *WaT_l, *ba_l0, *skip_l0, *xold;   // post: skip-source (x_op at l=0)
  float *xop, *P;
  const float *WqT_n, *bq_n0;                          // proj(l+1) y=0
  const float *CW_n, *CB_n;                            // proj(l+1) y=1..4 (4 mats)
  const float *part, *Wa_l1, *ba_l1, *skip_l1, *xvold; // vtail (xvold = x_v at l=0)
  float *xv, *outsv_l, *qv;
  const float *Wq_n1, *bq_n1;                          // qv(l+1) rowproj
  int do_proj;
};

__launch_bounds__(256)
__global__ void k_fused(FArgs f) {
  __shared__ float As[64][36];
  __shared__ float Bs[32][132];
  const int t = threadIdx.x;
  if (blockIdx.x >= NN / 64) {
    // ---- vnode tail: edge1red + gelu + Wa[l,1] + skip -> xv, outsv; then qv(l+1) ----
    __shared__ float xr[HID], xn[HID];
    int v = blockIdx.x - NN / 64;
    if (t < 64) {
      float a0 = 0.f, a1 = 0.f, ws2 = 0.f;
      for (int s = 0; s < 32; ++s) {
        const float* p = f.part + (size_t)(v * 32 + s) * 192;
        a0 += p[t]; a1 += p[64 + t]; ws2 += p[128 + t];
      }
      float inv = 1.0f / (ws2 + 1e-16f);
      xr[2 * t]     = gelu_f(a0 * inv);
      xr[2 * t + 1] = gelu_f(a1 * inv);
    }
    __syncthreads();
    if (t < HID) {
      float s = f.ba_l1[t];
      const float4* wr = (const float4*)(f.Wa_l1 + (size_t)t * HID);
      const float4* xx = (const float4*)xr;
      #pragma unroll 8
      for (int c = 0; c < HID / 4; ++c) {
        float4 w4 = wr[c], x4 = xx[c];
        s += x4.x * w4.x + x4.y * w4.y + x4.z * w4.z + x4.w * w4.w;
      }
      float gg = sigmoid_f(*f.skip_l1);
      float nv2 = gg * s + (1.f - gg) * f.xvold[v * HID + t];
      f.xv[v * HID + t] = nv2;
      f.outsv_l[v * HID + t] = nv2;
      xn[t] = nv2;
    }
    __syncthreads();
    if (f.do_proj && t < HID) {
      float s = f.bq_n1[t];
      const float4* wr = (const float4*)(f.Wq_n1 + (size_t)t * HID);
      const float4* xx = (const float4*)xn;
      #pragma unroll 8
      for (int c = 0; c < HID / 4; ++c) {
        float4 w4 = wr[c], x4 = xx[c];
        s += x4.x * w4.x + x4.y * w4.y + x4.z * w4.z + x4.w * w4.w;
      }
      f.qv[v * HID + t] = s;
    }
    return;
  }
  const int m0 = blockIdx.x * 64;
  // post(l): xop = g*(gelu(agg)@WaT+ba) + (1-g)*xold
  gemm_tile(As, Bs, t, f.agg, f.WaT_l, f.ba_l0, f.xop, HID, 0, m0, 1, f.skip_l0, f.xold);
  if (!f.do_proj) return;
  __threadfence_block();   // make own-block global writes to xop visible in-block
  __syncthreads();
  // proj(l+1): 5 weight slices for the same rows (xop tile is L1-hot)
  gemm_tile(As, Bs, t, f.xop, f.WqT_n, f.bq_n0, f.P, PST, 0, m0, 0, nullptr, nullptr);
  #pragma unroll 1
  for (int y = 1; y < 5; ++y)
    gemm_tile(As, Bs, t, f.xop, f.CW_n + (size_t)(y - 1) * HID * HID,
              f.CB_n + (y - 1) * HID, f.P, PST, y * HID, m0, 0, nullptr, nullptr);
}

// ================= JK attention + node/graph MLPs =============================================
struct TailW {
  const float *win, *bin, *wout, *bout;
  const float *nw0, *nb0, *nw1, *nb1, *nw2, *nb2, *nw3, *nb3, *nw4, *nb4, *nw5, *nb5, *nw6, *nb6;
  const float *gw0, *gb0, *gw1, *gb1;
};

__launch_bounds__(128)
__global__ void k_final(const float* __restrict__ outsv, TailW tw, float* __restrict__ outp) {
  __shared__ float xs[4][HID], qq[4][HID], kk[4][HID], vv[4][HID], oo[4][HID];
  __shared__ float att[NH][4][4];
  __shared__ float hb[HID], tb[64];
  int b = blockIdx.x, t = threadIdx.x;
  for (int l = 0; l < 4; ++l) xs[l][t] = outsv[(size_t)(l * NV + b) * HID + t];
  __syncthreads();
  for (int l = 0; l < 4; ++l) {
    float sq = tw.bin[t], sk = tw.bin[t + 128], sv = tw.bin[t + 256];
    const float* wq = tw.win + (size_t)t * HID;
    const float* wk = tw.win + (size_t)(t + 128) * HID;
    const float* wv = tw.win + (size_t)(t + 256) * HID;
    for (int c = 0; c < HID; ++c) {
      float x = xs[l][c];
      sq += x * wq[c]; sk += x * wk[c]; sv += x * wv[c];
    }
    qq[l][t] = sq; kk[l][t] = sk; vv[l][t] = sv;
  }
  __syncthreads();
  {
    int h = t >> 4, ql = (t >> 2) & 3, kl = t & 3;
    float s = 0.f;
    #pragma unroll
    for (int d = 0; d < DH; ++d) s += qq[ql][h * DH + d] * kk[kl][h * DH + d];
    att[h][ql][kl] = s * SCALE;
  }
  __syncthreads();
  if (t < 32) {
    int h = t >> 2, ql = t & 3;
    float m = att[h][ql][0];
    for (int k2 = 1; k2 < 4; ++k2) m = fmaxf(m, att[h][ql][k2]);
    float e[4], s = 0.f;
    for (int k2 = 0; k2 < 4; ++k2) { e[k2] = __expf(att[h][ql][k2] - m); s += e[k2]; }
    for (int k2 = 0; k2 < 4; ++k2) att[h][ql][k2] = e[k2] / s;
  }
  __syncthreads();
  {
    int h = t >> 4;
    #pragma unroll
    for (int ql = 0; ql < 4; ++ql) {
      float s = 0.f;
      #pragma unroll
      for (int kl = 0; kl < 4; ++kl) s += att[h][ql][kl] * vv[kl][t];
      oo[ql][t] = s;
    }
  }
  __syncthreads();
  {
    float s = 0.f;
    const float* wr = tw.wout + (size_t)t * HID;
    for (int l = 0; l < 4; ++l) {
      float ss = tw.bout[t];
      for (int c = 0; c < HID; ++c) ss += oo[l][c] * wr[c];
      s += ss;
    }
    hb[t] = s;
  }
  __syncthreads();
  if (t < 64) { float s = tw.nb0[t]; const float* wr = tw.nw0 + t * 128; for (int c = 0; c < 128; ++c) s += hb[c] * wr[c]; tb[t] = gelu_f(s); }
  __syncthreads();
  if (t < 32) { float s = tw.nb1[t]; const float* wr = tw.nw1 + t * 64;  for (int c = 0; c < 64;  ++c) s += tb[c] * wr[c]; hb[t] = gelu_f(s); }
  __syncthreads();
  if (t < 16) { float s = tw.nb2[t]; const float* wr = tw.nw2 + t * 32;  for (int c = 0; c < 32;  ++c) s += hb[c] * wr[c]; tb[t] = gelu_f(s); }
  __syncthreads();
  if (t < 8)  { float s = tw.nb3[t]; const float* wr = tw.nw3 + t * 16;  for (int c = 0; c < 16;  ++c) s += tb[c] * wr[c]; hb[t] = gelu_f(s); }
  __syncthreads();
  if (t < 4)  { float s = tw.nb4[t]; const float* wr = tw.nw4 + t * 8;   for (int c = 0; c < 8;   ++c) s += hb[c] * wr[c]; tb[t] = gelu_f(s); }
  __syncthreads();
  if (t < 2)  { float s = tw.nb5[t]; const float* wr = tw.nw5 + t * 4;   for (int c = 0; c < 4;   ++c) s += tb[c] * wr[c]; hb[t] = gelu_f(s); }
  __syncthreads();
  if (t == 0) {
    float s = hb[0] * tw.nw6[0] + hb[1] * tw.nw6[1] + tw.nb6[0];
    float g0 = gelu_f(s * tw.gw0[0] + tw.gb0[0]);
    float g1 = gelu_f(s * tw.gw0[1] + tw.gb0[1]);
    outp[b] = g0 * tw.gw1[0] + g1 * tw.gw1[1] + tw.gb1[0];
  }
}

// ================= host =======================================================================
extern "C" void kernel_launch(void* const* d_in, const int* in_sizes, int n_in,
                              void* d_out, int out_size, void* d_ws, size_t ws_size,
                              hipStream_t stream) {
  const float* x_op = (const float*)d_in[0];
  const float* x_v  = (const float*)d_in[1];
  const int*   ei0  = (const int*)d_in[2];
  const int*   ei1  = (const int*)d_in[3];
  const float* Wk   = (const float*)d_in[4];
  const float* Wq   = (const float*)d_in[5];
  const float* Wv   = (const float*)d_in[6];
  const float* Wa   = (const float*)d_in[7];
  const float* bk   = (const float*)d_in[8];
  const float* bq   = (const float*)d_in[9];
  const float* bv   = (const float*)d_in[10];
  const float* ba   = (const float*)d_in[11];
  const float* skip = (const float*)d_in[12];
  const float* a_rel = (const float*)d_in[13];
  const float* m_rel = (const float*)d_in[14];
  const float* p_rel = (const float*)d_in[15];
  (void)in_sizes; (void)n_in; (void)out_size; (void)ws_size;

  char* wsp = (char*)d_ws;
  size_t off = 0;
  auto alloc = [&](size_t bytes) -> void* {
    void* p = wsp + off;
    off += (bytes + 255) & ~(size_t)255;
    return p;
  };
  float* P     = (float*)alloc((size_t)NN * PST * 4);
  float* xop   = (float*)alloc((size_t)NN * HID * 4);
  float* agg   = (float*)alloc((size_t)NN * HID * 4);
  float* CW    = (float*)alloc((size_t)16 * HID * HID * 4);
  float* CB    = (float*)alloc((size_t)16 * HID * 4);
  float* WqT   = (float*)alloc((size_t)NL * HID * HID * 4);
  float* WaT   = (float*)alloc((size_t)NL * HID * HID * 4);
  float* xv    = (float*)alloc((size_t)NV * HID * 4);
  float* qv    = (float*)alloc((size_t)NV * HID * 4);
  float* outsv = (float*)alloc((size_t)NL * NV * HID * 4);
  float* part  = (float*)alloc((size_t)NV * 32 * 192 * 4);
  int* rowptr0 = (int*)alloc((size_t)(NN + 1) * 4);
  int* cur0    = (int*)alloc((size_t)NN * 4);
  int* col0    = (int*)alloc((size_t)E0E * 4);
  int* rowptr1 = (int*)alloc((size_t)(NV + 1) * 4);
  int* cur1    = (int*)alloc((size_t)NV * 4);
  int* col1    = (int*)alloc((size_t)NN * 4);

  // setup (ws re-poisoned every call -> rebuild each time); no x copies (layer 0 reads inputs)
  k_setup<<<152, 256, 0, stream>>>(cur0, cur1, Wk, Wv, bk, bv, a_rel, m_rel, p_rel,
                                   CW, CB, Wq, Wa, WqT, WaT);
  k_hist2<<<E0E / 1024 + NN / 1024, 256, 0, stream>>>(ei0 + E0E, ei1 + NN, cur0, cur1);
  k_scan2<<<2, 1024, 0, stream>>>(cur0, rowptr0, cur1, rowptr1);
  k_scat2<<<E0E / 1024 + NN / 1024, 256, 0, stream>>>(ei0, ei0 + E0E, cur0, col0,
                                                      ei1, ei1 + NN, cur1, col1);

  // layer-0 projection straight from inputs
  WSet wp;
  wp.w[0] = WqT; wp.b[0] = bq;
  for (int m = 0; m < 4; ++m) { wp.w[1 + m] = CW + (size_t)m * HID * HID; wp.b[1 + m] = CB + m * HID; }
  k_proj0<<<dim3(NN / 64, 6), 256, 0, stream>>>(x_op, wp, P,
                                                Wq + (size_t)1 * HID * HID, bq + HID, x_v, qv);

  for (int l = 0; l < NL; ++l) {
    k_edges<<<NN / 4 + NV * 8, 256, 0, stream>>>(P, rowptr0, col0, agg, qv, rowptr1, col1, part);
    FArgs f;
    f.agg = agg;
    f.WaT_l = WaT + (size_t)l * HID * HID;
    f.ba_l0 = ba + (l * 2 + 0) * HID;
    f.skip_l0 = skip + l * 2 + 0;
    f.xold = (l == 0) ? x_op : xop;
    f.xop = xop; f.P = P;
    int ln = l + 1;
    f.WqT_n = WqT + (size_t)(ln & 3) * HID * HID;
    f.bq_n0 = bq + ((ln & 3) * 2 + 0) * HID;
    f.CW_n = CW + (size_t)(ln & 3) * 4 * HID * HID;
    f.CB_n = CB + (ln & 3) * 4 * HID;
    f.part = part;
    f.Wa_l1 = Wa + (size_t)(l * 2 + 1) * HID * HID;
    f.ba_l1 = ba + (l * 2 + 1) * HID;
    f.skip_l1 = skip + l * 2 + 1;
    f.xvold = (l == 0) ? x_v : xv;
    f.xv = xv;
    f.outsv_l = outsv + (size_t)l * NV * HID;
    f.qv = qv;
    f.Wq_n1 = Wq + (size_t)((ln & 3) * 2 + 1) * HID * HID;
    f.bq_n1 = bq + ((ln & 3) * 2 + 1) * HID;
    f.do_proj = (l < NL - 1) ? 1 : 0;
    k_fused<<<NN / 64 + NV, 256, 0, stream>>>(f);
  }

  TailW tw;
  tw.win  = (const float*)d_in[16]; tw.bin  = (const float*)d_in[17];
  tw.wout = (const float*)d_in[18]; tw.bout = (const float*)d_in[19];
  tw.nw0 = (const float*)d_in[20]; tw.nb0 = (const float*)d_in[21];
  tw.nw1 = (const float*)d_in[22]; tw.nb1 = (const float*)d_in[23];
  tw.nw2 = (const float*)d_in[24]; tw.nb2 = (const float*)d_in[25];
  tw.nw3 = (const float*)d_in[26]; tw.nb3 = (const float*)d_in[27];
  tw.nw4 = (const float*)d_in[28]; tw.nb4 = (const float*)d_in[29];
  tw.nw5 = (const float*)d_in[30]; tw.nb5 = (const float*)d_in[31];
  tw.nw6 = (const float*)d_in[32]; tw.nb6 = (const float*)d_in[33];
  tw.gw0 = (const float*)d_in[34]; tw.gb0 = (const float*)d_in[35];
  tw.gw1 = (const float*)d_in[36]; tw.gb1 = (const float*)d_in[37];
  k_final<<<NV, 128, 0, stream>>>(outsv, tw, (float*)d_out);
}

// Round 13
// 985.521 us; speedup vs baseline: 2.5696x; 1.0456x over previous
//
#include <hip/hip_runtime.h>

#define NN   32768
#define NV   64
#define E0E  524288
#define HID  128
#define NL   4
#define NH   8
#define DH   16
#define SCALE 0.25f
#define PST  640   // P row stride: [q | k0 | v0 | k1 | v1]
#define LDA  136   // bf16 row stride for staged A (16B-aligned frag reads)

typedef __attribute__((ext_vector_type(8))) short short8;   // 8 bf16 = 4 VGPRs
typedef __attribute__((ext_vector_type(4))) float f32x4;

__device__ __forceinline__ float gelu_f(float x) {
  return 0.5f * x * (1.0f + erff(x * 0.7071067811865475f));
}
__device__ __forceinline__ float sigmoid_f(float x) {
  return 1.0f / (1.0f + __expf(-x));
}
__device__ __forceinline__ unsigned short f2bf(float x) {   // RN-even f32->bf16
  unsigned u = __float_as_uint(x);
  return (unsigned short)((u + 0x7FFFu + ((u >> 16) & 1u)) >> 16);
}
__device__ __forceinline__ float bf2f(unsigned short h) {
  return __uint_as_float(((unsigned)h) << 16);
}

union SMu {
  struct { unsigned short Ah[64][LDA]; unsigned short Al[64][LDA]; } a;  // 34816 B
  struct { float xr[HID]; float xn[HID]; } v;
};

// ---- stage 64xK=128 fp32 tile into split hi/lo bf16 LDS (coalesced float4 reads) ----
__device__ __forceinline__ void stage_A(unsigned short Ah[][LDA], unsigned short Al[][LDA],
                                        int t, const float* __restrict__ A, int m0, int gelu) {
  #pragma unroll
  for (int i = 0; i < 8; ++i) {
    int idx = t + 256 * i;            // float4 index over 64x32
    int m = idx >> 5, c4 = (idx & 31) * 4;
    float4 v = *(const float4*)(A + (size_t)(m0 + m) * HID + c4);
    if (gelu) { v.x = gelu_f(v.x); v.y = gelu_f(v.y); v.z = gelu_f(v.z); v.w = gelu_f(v.w); }
    unsigned short h0 = f2bf(v.x), h1 = f2bf(v.y), h2 = f2bf(v.z), h3 = f2bf(v.w);
    *(ushort4*)&Ah[m][c4] = make_ushort4(h0, h1, h2, h3);
    *(ushort4*)&Al[m][c4] = make_ushort4(f2bf(v.x - bf2f(h0)), f2bf(v.y - bf2f(h1)),
                                         f2bf(v.z - bf2f(h2)), f2bf(v.w - bf2f(h3)));
  }
}

// ---- MFMA split-bf16 GEMM: 64x128 tile, K=128. Wf = frag-ordered weights (hi plane,
// then lo plane at +16384). 4 waves, each: 16-row m-strip x 8 n-tiles of 16. ----
__device__ __forceinline__ void mfma_compute(const unsigned short Ah[][LDA],
    const unsigned short Al[][LDA], int t, const unsigned short* __restrict__ Wf,
    const float* __restrict__ bias, float* __restrict__ out, int ldo, int cbase, int m0,
    const float* __restrict__ skipv, const float* __restrict__ skipsrc) {
  const int w = t >> 6, lane = t & 63, c16 = lane & 15, quad = lane >> 4;
  f32x4 acc[8] = {};
  #pragma unroll
  for (int ks = 0; ks < 4; ++ks) {
    short8 ah = *(const short8*)&Ah[16 * w + c16][ks * 32 + quad * 8];
    short8 al = *(const short8*)&Al[16 * w + c16][ks * 32 + quad * 8];
    #pragma unroll
    for (int nt = 0; nt < 8; ++nt) {
      const unsigned short* bp = Wf + (size_t)((nt * 4 + ks) * 64 + lane) * 8;
      short8 bh = *(const short8*)bp;
      short8 bl = *(const short8*)(bp + 16384);
      acc[nt] = __builtin_amdgcn_mfma_f32_16x16x32_bf16(ah, bh, acc[nt], 0, 0, 0);
      acc[nt] = __builtin_amdgcn_mfma_f32_16x16x32_bf16(ah, bl, acc[nt], 0, 0, 0);
      acc[nt] = __builtin_amdgcn_mfma_f32_16x16x32_bf16(al, bh, acc[nt], 0, 0, 0);
    }
  }
  float g = 0.f, gm1 = 0.f;
  if (skipv) { g = sigmoid_f(*skipv); gm1 = 1.0f - g; }
  #pragma unroll
  for (int nt = 0; nt < 8; ++nt) {
    int col = cbase + nt * 16 + c16;
    float bb = bias[nt * 16 + c16];
    #pragma unroll
    for (int r = 0; r < 4; ++r) {
      int m = m0 + 16 * w + quad * 4 + r;   // C/D: row = quad*4 + reg, col = lane&15
      float v = acc[nt][r] + bb;
      if (skipv) v = g * v + gm1 * skipsrc[(size_t)m * ldo + col];
      out[(size_t)m * ldo + col] = v;
    }
  }
}

// ================= setup: zero counters + weight-combine (natural [n][k]) =====================
__global__ __launch_bounds__(256) void k_setup(
    int* __restrict__ cur0, int* __restrict__ cur1,
    const float* __restrict__ Wk, const float* __restrict__ Wv,
    const float* __restrict__ bk, const float* __restrict__ bv,
    const float* __restrict__ a_rel, const float* __restrict__ m_rel,
    const float* __restrict__ p_rel,
    float* __restrict__ CW, float* __restrict__ CB) {
  int b = blockIdx.x, t = threadIdx.x;
  if (b < 128) { int i = b * 256 + t; cur0[i] = 0; if (i < NV) cur1[i] = 0; return; }
  b -= 128;
  {
    int blk = b;                   // 0..15
    int l = blk >> 2, mat = blk & 3;
    int rel = mat >> 1;
    int isK = ((mat & 1) == 0);
    const float* W  = (isK ? Wk : Wv) + (size_t)(l * 2) * HID * HID;
    const float* bb = (isK ? bk : bv) + (l * 2) * HID;
    const float* R  = (isK ? a_rel : m_rel) + (size_t)((l * 2 + rel) * NH) * DH * DH;
    float* cw = CW + (size_t)blk * HID * HID;
    float* cb = CB + blk * HID;
    for (int o = t; o < HID * HID; o += 256) {
      int j = o >> 7, c = o & 127;
      int h = j >> 4, e = j & 15;
      float sc = isK ? (p_rel[(l * 2 + rel) * NH + h] * SCALE) : 1.0f;
      float s = 0.f;
      #pragma unroll
      for (int d = 0; d < DH; ++d)
        s += W[(size_t)(h * DH + d) * HID + c] * R[h * 256 + d * 16 + e];
      cw[(size_t)j * HID + c] = s * sc;   // [n][k]
    }
    if (t < HID) {
      int j = t, h = j >> 4, e = j & 15;
      float sc = isK ? (p_rel[(l * 2 + rel) * NH + h] * SCALE) : 1.0f;
      float s = 0.f;
      #pragma unroll
      for (int d = 0; d < DH; ++d) s += bb[h * DH + d] * R[h * 256 + d * 16 + e];
      cb[j] = s * sc;
    }
  }
}

// ================= frag-order + split all 24 weight mats (CW 0-15, Wq0 16-19, Wa0 20-23) ======
__global__ __launch_bounds__(256) void k_frag(const float* __restrict__ CW,
                                              const float* __restrict__ Wq,
                                              const float* __restrict__ Wa,
                                              unsigned short* __restrict__ FW) {
  int m = blockIdx.x, t = threadIdx.x;
  const float* src = (m < 16) ? (CW + (size_t)m * HID * HID)
                   : (m < 20) ? (Wq + (size_t)((m - 16) * 2) * HID * HID)
                              : (Wa + (size_t)((m - 20) * 2) * HID * HID);
  unsigned short* hi = FW + (size_t)m * 32768;
  unsigned short* lo = hi + 16384;
  for (int idx = t; idx < 16384; idx += 256) {
    int j = idx & 7, lane = (idx >> 3) & 63, ks = (idx >> 9) & 3, nt = idx >> 11;
    int n = nt * 16 + (lane & 15);
    int k = ks * 32 + (lane >> 4) * 8 + j;
    float x = src[(size_t)n * HID + k];
    unsigned short h = f2bf(x);
    hi[idx] = h;
    lo[idx] = f2bf(x - bf2f(h));
  }
}

// ================= histograms (4 edges/thread) ================================================
__global__ __launch_bounds__(256) void k_hist2(const int* __restrict__ dst0,
                                               const int* __restrict__ dst1,
                                               int* __restrict__ cur0, int* __restrict__ cur1) {
  int b = blockIdx.x, t = threadIdx.x;
  if (b < E0E / 1024) {
    int base = b * 1024 + t;
    #pragma unroll
    for (int i = 0; i < 4; ++i) atomicAdd(&cur0[dst0[base + i * 256]], 1);
  } else {
    int base = (b - E0E / 1024) * 1024 + t;
    #pragma unroll
    for (int i = 0; i < 4; ++i) atomicAdd(&cur1[dst1[base + i * 256]], 1);
  }
}

// ================= scans ======================================================================
__global__ __launch_bounds__(1024) void k_scan2(int* __restrict__ cnt0, int* __restrict__ rp0,
                                                int* __restrict__ cnt1, int* __restrict__ rp1) {
  __shared__ int sd[1024];
  int t = threadIdx.x;
  if (blockIdx.x == 0) {
    int loc[32];
    int base = t * 32, s = 0;
    #pragma unroll
    for (int i = 0; i < 32; ++i) { loc[i] = cnt0[base + i]; s += loc[i]; }
    sd[t] = s;
    __syncthreads();
    for (int off = 1; off < 1024; off <<= 1) {
      int v = (t >= off) ? sd[t - off] : 0;
      __syncthreads();
      sd[t] += v;
      __syncthreads();
    }
    int run = sd[t] - s;
    #pragma unroll
    for (int i = 0; i < 32; ++i) { rp0[base + i] = run; cnt0[base + i] = run; run += loc[i]; }
    if (t == 1023) rp0[NN] = E0E;
  } else if (t < 64) {
    int v = cnt1[t];
    int s = v;
    #pragma unroll
    for (int off = 1; off < 64; off <<= 1) {
      int u = __shfl_up(s, off);
      if (t >= off) s += u;
    }
    int ex = s - v;
    rp1[t] = ex; cnt1[t] = ex;
    if (t == 63) rp1[NV] = NN;
  }
}

// ================= scatters (4 edges/thread) ==================================================
__global__ __launch_bounds__(256) void k_scat2(const int* __restrict__ src0,
                                               const int* __restrict__ dst0,
                                               int* __restrict__ cur0, int* __restrict__ col0,
                                               const int* __restrict__ src1,
                                               const int* __restrict__ dst1,
                                               int* __restrict__ cur1, int* __restrict__ col1) {
  int b = blockIdx.x, t = threadIdx.x;
  if (b < E0E / 1024) {
    int base = b * 1024 + t;
    #pragma unroll
    for (int i = 0; i < 4; ++i) {
      int e = base + i * 256;
      int pos = atomicAdd(&cur0[dst0[e]], 1);
      col0[pos] = src0[e];
    }
  } else {
    int base = (b - E0E / 1024) * 1024 + t;
    #pragma unroll
    for (int i = 0; i < 4; ++i) {
      int e = base + i * 256;
      int pos = atomicAdd(&cur1[dst1[e]], 1);
      col1[pos] = src1[e];
    }
  }
}

// ================= k_proj0: layer-0 projection via MFMA (reads x_op directly) =================
__launch_bounds__(256)
__global__ void k_proj0(const float* __restrict__ A, const unsigned short* __restrict__ WqF,
                        const unsigned short* __restrict__ CWF,
                        const float* __restrict__ bq0, const float* __restrict__ CB,
                        float* __restrict__ P,
                        const float* __restrict__ rpW, const float* __restrict__ rpB,
                        const float* __restrict__ rpX, float* __restrict__ qvout) {
  __shared__ SMu sm;
  const int t = threadIdx.x;
  if (blockIdx.x >= NN / 64) {     // rowproj: qv0 = x_v @ Wq[0,1]^T + bq
    int n = blockIdx.x - NN / 64;
    if (t < HID) sm.v.xr[t] = rpX[n * HID + t];
    __syncthreads();
    if (t < HID) {
      float s = rpB[t];
      const float4* wr = (const float4*)(rpW + (size_t)t * HID);
      const float4* xx = (const float4*)sm.v.xr;
      #pragma unroll 8
      for (int c = 0; c < HID / 4; ++c) {
        float4 w4 = wr[c], x4 = xx[c];
        s += x4.x * w4.x + x4.y * w4.y + x4.z * w4.z + x4.w * w4.w;
      }
      qvout[n * HID + t] = s;
    }
    return;
  }
  const int m0 = blockIdx.x * 64;
  stage_A(sm.a.Ah, sm.a.Al, t, A, m0, 0);
  __syncthreads();
  mfma_compute(sm.a.Ah, sm.a.Al, t, WqF, bq0, P, PST, 0, m0, nullptr, nullptr);
  #pragma unroll 1
  for (int y = 1; y < 5; ++y)
    mfma_compute(sm.a.Ah, sm.a.Al, t, CWF + (size_t)(y - 1) * 32768,
                 CB + (y - 1) * HID, P, PST, y * HID, m0, nullptr, nullptr);
}

// ================= k_edges: edge0 (blocks < NN/4) + edge1 (NN/4 .. +512) — r8 best form =======
__launch_bounds__(256)
__global__ void k_edges(const float* __restrict__ P, const int* __restrict__ rowptr0,
                        const int* __restrict__ col0, float* __restrict__ agg,
                        const float* __restrict__ qv, const int* __restrict__ rowptr1,
                        const int* __restrict__ col1, float* __restrict__ part) {
  int lane = threadIdx.x & 63;
  if (blockIdx.x < NN / 4) {
    int n = blockIdx.x * 4 + (threadIdx.x >> 6);
    float2 q = *(const float2*)(P + (size_t)n * PST + 2 * lane);
    int e0 = rowptr0[n], e1 = rowptr0[n + 1];
    float acc0 = 0.f, acc1 = 0.f, wsum = 0.f;
    int e = e0;
    for (; e + 8 <= e1; e += 8) {
      const float* r[8];
      #pragma unroll
      for (int u = 0; u < 8; ++u) r[u] = P + (size_t)col0[e + u] * PST + 2 * lane;
      float2 kx[8], vx[8];
      #pragma unroll
      for (int u = 0; u < 8; ++u) kx[u] = *(const float2*)(r[u] + 128);
      #pragma unroll
      for (int u = 0; u < 8; ++u) vx[u] = *(const float2*)(r[u] + 256);
      float p[8];
      #pragma unroll
      for (int u = 0; u < 8; ++u) p[u] = q.x * kx[u].x + q.y * kx[u].y;
      #pragma unroll
      for (int u = 0; u < 8; ++u) {
        p[u] += __shfl_xor(p[u], 1); p[u] += __shfl_xor(p[u], 2); p[u] += __shfl_xor(p[u], 4);
      }
      #pragma unroll
      for (int u = 0; u < 8; ++u) {
        float w = __expf(p[u]);
        wsum += w; acc0 += w * vx[u].x; acc1 += w * vx[u].y;
      }
    }
    for (; e < e1; ++e) {
      const float* row = P + (size_t)col0[e] * PST + 2 * lane;
      float2 kv = *(const float2*)(row + 128);
      float p = q.x * kv.x + q.y * kv.y;
      p += __shfl_xor(p, 1); p += __shfl_xor(p, 2); p += __shfl_xor(p, 4);
      float w = __expf(p);
      float2 vv = *(const float2*)(row + 256);
      wsum += w; acc0 += w * vv.x; acc1 += w * vv.y;
    }
    float inv = 1.0f / (wsum + 1e-16f);
    *(float2*)(agg + (size_t)n * HID + 2 * lane) = make_float2(acc0 * inv, acc1 * inv);
  } else {
    int b2 = blockIdx.x - NN / 4;
    int g = b2 >> 3, ch = b2 & 7;
    int w = threadIdx.x >> 6;
    int slot = ch * 4 + w;
    float2 q = *(const float2*)(qv + g * HID + 2 * lane);
    int e0 = rowptr1[g], e1 = rowptr1[g + 1];
    int tot = e1 - e0;
    int len = (tot + 31) >> 5;
    int s0 = e0 + slot * len;
    int s1 = s0 + len; if (s1 > e1) s1 = e1;
    float acc0 = 0.f, acc1 = 0.f, wsum = 0.f;
    int e = s0;
    for (; e + 4 <= s1; e += 4) {
      const float* ra = P + (size_t)col1[e]     * PST + 2 * lane;
      const float* rb = P + (size_t)col1[e + 1] * PST + 2 * lane;
      const float* rc = P + (size_t)col1[e + 2] * PST + 2 * lane;
      const float* rd = P + (size_t)col1[e + 3] * PST + 2 * lane;
      float2 ka = *(const float2*)(ra + 384);
      float2 kb = *(const float2*)(rb + 384);
      float2 kc = *(const float2*)(rc + 384);
      float2 kd = *(const float2*)(rd + 384);
      float2 va = *(const float2*)(ra + 512);
      float2 vb = *(const float2*)(rb + 512);
      float2 vc = *(const float2*)(rc + 512);
      float2 vd = *(const float2*)(rd + 512);
      float pa = q.x * ka.x + q.y * ka.y;
      float pb = q.x * kb.x + q.y * kb.y;
      float pc = q.x * kc.x + q.y * kc.y;
      float pd = q.x * kd.x + q.y * kd.y;
      pa += __shfl_xor(pa, 1); pb += __shfl_xor(pb, 1); pc += __shfl_xor(pc, 1); pd += __shfl_xor(pd, 1);
      pa += __shfl_xor(pa, 2); pb += __shfl_xor(pb, 2); pc += __shfl_xor(pc, 2); pd += __shfl_xor(pd, 2);
      pa += __shfl_xor(pa, 4); pb += __shfl_xor(pb, 4); pc += __shfl_xor(pc, 4); pd += __shfl_xor(pd, 4);
      float wa = __expf(pa), wb = __expf(pb), wc = __expf(pc), wd = __expf(pd);
      wsum += (wa + wb) + (wc + wd);
      acc0 += wa * va.x + wb * vb.x + wc * vc.x + wd * vd.x;
      acc1 += wa * va.y + wb * vb.y + wc * vc.y + wd * vd.y;
    }
    for (; e < s1; ++e) {
      const float* row = P + (size_t)col1[e] * PST + 2 * lane;
      float2 kv = *(const float2*)(row + 384);
      float p = q.x * kv.x + q.y * kv.y;
      p += __shfl_xor(p, 1); p += __shfl_xor(p, 2); p += __shfl_xor(p, 4);
      float ww = __expf(p);
      float2 vv = *(const float2*)(row + 512);
      wsum += ww; acc0 += ww * vv.x; acc1 += ww * vv.y;
    }
    float* pp = part + (size_t)(g * 32 + slot) * 192;
    pp[lane] = acc0; pp[64 + lane] = acc1; pp[128 + lane] = wsum;
  }
}

// ================= k_fused: post(l) then proj(l+1) for same rows, MFMA ========================
struct FArgs {
  const float *agg; const unsigned short *WaF_l; const float *ba_l0, *skip_l0, *xold;
  float *xop, *P;
  const unsigned short *WqF_n; const float *bq_n0;
  const unsigned short *CWF_n; const float *CB_n;
  const float *part, *Wa_l1, *ba_l1, *skip_l1, *xvold;
  float *xv, *outsv_l, *qv;
  const float *Wq_n1, *bq_n1;
  int do_proj;
};

__launch_bounds__(256)
__global__ void k_fused(FArgs f) {
  __shared__ SMu sm;
  const int t = threadIdx.x;
  if (blockIdx.x >= NN / 64) {
    // ---- vnode tail: edge1red + gelu + Wa[l,1] + skip -> xv, outsv; then qv(l+1) ----
    int v = blockIdx.x - NN / 64;
    if (t < 64) {
      float a0 = 0.f, a1 = 0.f, ws2 = 0.f;
      for (int s = 0; s < 32; ++s) {
        const float* p = f.part + (size_t)(v * 32 + s) * 192;
        a0 += p[t]; a1 += p[64 + t]; ws2 += p[128 + t];
      }
      float inv = 1.0f / (ws2 + 1e-16f);
      sm.v.xr[2 * t]     = gelu_f(a0 * inv);
      sm.v.xr[2 * t + 1] = gelu_f(a1 * inv);
    }
    __syncthreads();
    if (t < HID) {
      float s = f.ba_l1[t];
      const float4* wr = (const float4*)(f.Wa_l1 + (size_t)t * HID);
      const float4* xx = (const float4*)sm.v.xr;
      #pragma unroll 8
      for (int c = 0; c < HID / 4; ++c) {
        float4 w4 = wr[c], x4 = xx[c];
        s += x4.x * w4.x + x4.y * w4.y + x4.z * w4.z + x4.w * w4.w;
      }
      float gg = sigmoid_f(*f.skip_l1);
      float nv2 = gg * s + (1.f - gg) * f.xvold[v * HID + t];
      f.xv[v * HID + t] = nv2;
      f.outsv_l[v * HID + t] = nv2;
      sm.v.xn[t] = nv2;
    }
    __syncthreads();
    if (f.do_proj && t < HID) {
      float s = f.bq_n1[t];
      const float4* wr = (const float4*)(f.Wq_n1 + (size_t)t * HID);
      const float4* xx = (const float4*)sm.v.xn;
      #pragma unroll 8
      for (int c = 0; c < HID / 4; ++c) {
        float4 w4 = wr[c], x4 = xx[c];
        s += x4.x * w4.x + x4.y * w4.y + x4.z * w4.z + x4.w * w4.w;
      }
      f.qv[v * HID + t] = s;
    }
    return;
  }
  const int m0 = blockIdx.x * 64;
  // post(l): xop = g*(gelu(agg)@Wa^T + ba) + (1-g)*xold
  stage_A(sm.a.Ah, sm.a.Al, t, f.agg, m0, 1);
  __syncthreads();
  mfma_compute(sm.a.Ah, sm.a.Al, t, f.WaF_l, f.ba_l0, f.xop, HID, 0, m0, f.skip_l0, f.xold);
  if (!f.do_proj) return;
  __threadfence_block();   // own-block global writes to xop visible in-block
  __syncthreads();
  // proj(l+1): stage xop tile once, run 5 weight slices
  stage_A(sm.a.Ah, sm.a.Al, t, f.xop, m0, 0);
  __syncthreads();
  mfma_compute(sm.a.Ah, sm.a.Al, t, f.WqF_n, f.bq_n0, f.P, PST, 0, m0, nullptr, nullptr);
  #pragma unroll 1
  for (int y = 1; y < 5; ++y)
    mfma_compute(sm.a.Ah, sm.a.Al, t, f.CWF_n + (size_t)(y - 1) * 32768,
                 f.CB_n + (y - 1) * HID, f.P, PST, y * HID, m0, nullptr, nullptr);
}

// ================= JK attention + node/graph MLPs =============================================
struct TailW {
  const float *win, *bin, *wout, *bout;
  const float *nw0, *nb0, *nw1, *nb1, *nw2, *nb2, *nw3, *nb3, *nw4, *nb4, *nw5, *nb5, *nw6, *nb6;
  const float *gw0, *gb0, *gw1, *gb1;
};

__launch_bounds__(128)
__global__ void k_final(const float* __restrict__ outsv, TailW tw, float* __restrict__ outp) {
  __shared__ float xs[4][HID], qq[4][HID], kk[4][HID], vv[4][HID], oo[4][HID];
  __shared__ float att[NH][4][4];
  __shared__ float hb[HID], tb[64];
  int b = blockIdx.x, t = threadIdx.x;
  for (int l = 0; l < 4; ++l) xs[l][t] = outsv[(size_t)(l * NV + b) * HID + t];
  __syncthreads();
  for (int l = 0; l < 4; ++l) {
    float sq = tw.bin[t], sk = tw.bin[t + 128], sv = tw.bin[t + 256];
    const float* wq = tw.win + (size_t)t * HID;
    const float* wk = tw.win + (size_t)(t + 128) * HID;
    const float* wv = tw.win + (size_t)(t + 256) * HID;
    for (int c = 0; c < HID; ++c) {
      float x = xs[l][c];
      sq += x * wq[c]; sk += x * wk[c]; sv += x * wv[c];
    }
    qq[l][t] = sq; kk[l][t] = sk; vv[l][t] = sv;
  }
  __syncthreads();
  {
    int h = t >> 4, ql = (t >> 2) & 3, kl = t & 3;
    float s = 0.f;
    #pragma unroll
    for (int d = 0; d < DH; ++d) s += qq[ql][h * DH + d] * kk[kl][h * DH + d];
    att[h][ql][kl] = s * SCALE;
  }
  __syncthreads();
  if (t < 32) {
    int h = t >> 2, ql = t & 3;
    float m = att[h][ql][0];
    for (int k2 = 1; k2 < 4; ++k2) m = fmaxf(m, att[h][ql][k2]);
    float e[4], s = 0.f;
    for (int k2 = 0; k2 < 4; ++k2) { e[k2] = __expf(att[h][ql][k2] - m); s += e[k2]; }
    for (int k2 = 0; k2 < 4; ++k2) att[h][ql][k2] = e[k2] / s;
  }
  __syncthreads();
  {
    int h = t >> 4;
    #pragma unroll
    for (int ql = 0; ql < 4; ++ql) {
      float s = 0.f;
      #pragma unroll
      for (int kl = 0; kl < 4; ++kl) s += att[h][ql][kl] * vv[kl][t];
      oo[ql][t] = s;
    }
  }
  __syncthreads();
  {
    float s = 0.f;
    const float* wr = tw.wout + (size_t)t * HID;
    for (int l = 0; l < 4; ++l) {
      float ss = tw.bout[t];
      for (int c = 0; c < HID; ++c) ss += oo[l][c] * wr[c];
      s += ss;
    }
    hb[t] = s;
  }
  __syncthreads();
  if (t < 64) { float s = tw.nb0[t]; const float* wr = tw.nw0 + t * 128; for (int c = 0; c < 128; ++c) s += hb[c] * wr[c]; tb[t] = gelu_f(s); }
  __syncthreads();
  if (t < 32) { float s = tw.nb1[t]; const float* wr = tw.nw1 + t * 64;  for (int c = 0; c < 64;  ++c) s += tb[c] * wr[c]; hb[t] = gelu_f(s); }
  __syncthreads();
  if (t < 16) { float s = tw.nb2[t]; const float* wr = tw.nw2 + t * 32;  for (int c = 0; c < 32;  ++c) s += hb[c] * wr[c]; tb[t] = gelu_f(s); }
  __syncthreads();
  if (t < 8)  { float s = tw.nb3[t]; const float* wr = tw.nw3 + t * 16;  for (int c = 0; c < 16;  ++c) s += tb[c] * wr[c]; hb[t] = gelu_f(s); }
  __syncthreads();
  if (t < 4)  { float s = tw.nb4[t]; const float* wr = tw.nw4 + t * 8;   for (int c = 0; c < 8;   ++c) s += hb[c] * wr[c]; tb[t] = gelu_f(s); }
  __syncthreads();
  if (t < 2)  { float s = tw.nb5[t]; const float* wr = tw.nw5 + t * 4;   for (int c = 0; c < 4;   ++c) s += tb[c] * wr[c]; hb[t] = gelu_f(s); }
  __syncthreads();
  if (t == 0) {
    float s = hb[0] * tw.nw6[0] + hb[1] * tw.nw6[1] + tw.nb6[0];
    float g0 = gelu_f(s * tw.gw0[0] + tw.gb0[0]);
    float g1 = gelu_f(s * tw.gw0[1] + tw.gb0[1]);
    outp[b] = g0 * tw.gw1[0] + g1 * tw.gw1[1] + tw.gb1[0];
  }
}

// ================= host =======================================================================
extern "C" void kernel_launch(void* const* d_in, const int* in_sizes, int n_in,
                              void* d_out, int out_size, void* d_ws, size_t ws_size,
                              hipStream_t stream) {
  const float* x_op = (const float*)d_in[0];
  const float* x_v  = (const float*)d_in[1];
  const int*   ei0  = (const int*)d_in[2];
  const int*   ei1  = (const int*)d_in[3];
  const float* Wk   = (const float*)d_in[4];
  const float* Wq   = (const float*)d_in[5];
  const float* Wv   = (const float*)d_in[6];
  const float* Wa   = (const float*)d_in[7];
  const float* bk   = (const float*)d_in[8];
  const float* bq   = (const float*)d_in[9];
  const float* bv   = (const float*)d_in[10];
  const float* ba   = (const float*)d_in[11];
  const float* skip = (const float*)d_in[12];
  const float* a_rel = (const float*)d_in[13];
  const float* m_rel = (const float*)d_in[14];
  const float* p_rel = (const float*)d_in[15];
  (void)in_sizes; (void)n_in; (void)out_size; (void)ws_size;

  char* wsp = (char*)d_ws;
  size_t off = 0;
  auto alloc = [&](size_t bytes) -> void* {
    void* p = wsp + off;
    off += (bytes + 255) & ~(size_t)255;
    return p;
  };
  float* P     = (float*)alloc((size_t)NN * PST * 4);
  float* xop   = (float*)alloc((size_t)NN * HID * 4);
  float* agg   = (float*)alloc((size_t)NN * HID * 4);
  float* CW    = (float*)alloc((size_t)16 * HID * HID * 4);
  float* CB    = (float*)alloc((size_t)16 * HID * 4);
  unsigned short* FW = (unsigned short*)alloc((size_t)24 * 32768 * 2);  // 1.57 MB frag weights
  float* xv    = (float*)alloc((size_t)NV * HID * 4);
  float* qv    = (float*)alloc((size_t)NV * HID * 4);
  float* outsv = (float*)alloc((size_t)NL * NV * HID * 4);
  float* part  = (float*)alloc((size_t)NV * 32 * 192 * 4);
  int* rowptr0 = (int*)alloc((size_t)(NN + 1) * 4);
  int* cur0    = (int*)alloc((size_t)NN * 4);
  int* col0    = (int*)alloc((size_t)E0E * 4);
  int* rowptr1 = (int*)alloc((size_t)(NV + 1) * 4);
  int* cur1    = (int*)alloc((size_t)NV * 4);
  int* col1    = (int*)alloc((size_t)NN * 4);

  k_setup<<<144, 256, 0, stream>>>(cur0, cur1, Wk, Wv, bk, bv, a_rel, m_rel, p_rel, CW, CB);
  k_frag<<<24, 256, 0, stream>>>(CW, Wq, Wa, FW);
  k_hist2<<<E0E / 1024 + NN / 1024, 256, 0, stream>>>(ei0 + E0E, ei1 + NN, cur0, cur1);
  k_scan2<<<2, 1024, 0, stream>>>(cur0, rowptr0, cur1, rowptr1);
  k_scat2<<<E0E / 1024 + NN / 1024, 256, 0, stream>>>(ei0, ei0 + E0E, cur0, col0,
                                                      ei1, ei1 + NN, cur1, col1);

  // layer-0 projection straight from inputs (MFMA)
  k_proj0<<<NN / 64 + NV, 256, 0, stream>>>(x_op, FW + (size_t)16 * 32768, FW,
                                            bq, CB, P,
                                            Wq + (size_t)1 * HID * HID, bq + HID, x_v, qv);

  for (int l = 0; l < NL; ++l) {
    k_edges<<<NN / 4 + NV * 8, 256, 0, stream>>>(P, rowptr0, col0, agg, qv, rowptr1, col1, part);
    FArgs f;
    f.agg = agg;
    f.WaF_l = FW + (size_t)(20 + l) * 32768;
    f.ba_l0 = ba + (l * 2 + 0) * HID;
    f.skip_l0 = skip + l * 2 + 0;
    f.xold = (l == 0) ? x_op : xop;
    f.xop = xop; f.P = P;
    int ln = (l + 1) & 3;
    f.WqF_n = FW + (size_t)(16 + ln) * 32768;
    f.bq_n0 = bq + (ln * 2 + 0) * HID;
    f.CWF_n = FW + (size_t)(ln * 4) * 32768;
    f.CB_n = CB + ln * 4 * HID;
    f.part = part;
    f.Wa_l1 = Wa + (size_t)(l * 2 + 1) * HID * HID;
    f.ba_l1 = ba + (l * 2 + 1) * HID;
    f.skip_l1 = skip + l * 2 + 1;
    f.xvold = (l == 0) ? x_v : xv;
    f.xv = xv;
    f.outsv_l = outsv + (size_t)l * NV * HID;
    f.qv = qv;
    f.Wq_n1 = Wq + (size_t)(ln * 2 + 1) * HID * HID;
    f.bq_n1 = bq + (ln * 2 + 1) * HID;
    f.do_proj = (l < NL - 1) ? 1 : 0;
    k_fused<<<NN / 64 + NV, 256, 0, stream>>>(f);
  }

  TailW tw;
  tw.win  = (const float*)d_in[16]; tw.bin  = (const float*)d_in[17];
  tw.wout = (const float*)d_in[18]; tw.bout = (const float*)d_in[19];
  tw.nw0 = (const float*)d_in[20]; tw.nb0 = (const float*)d_in[21];
  tw.nw1 = (const float*)d_in[22]; tw.nb1 = (const float*)d_in[23];
  tw.nw2 = (const float*)d_in[24]; tw.nb2 = (const float*)d_in[25];
  tw.nw3 = (const float*)d_in[26]; tw.nb3 = (const float*)d_in[27];
  tw.nw4 = (const float*)d_in[28]; tw.nb4 = (const float*)d_in[29];
  tw.nw5 = (const float*)d_in[30]; tw.nb5 = (const float*)d_in[31];
  tw.nw6 = (const float*)d_in[32]; tw.nb6 = (const float*)d_in[33];
  tw.gw0 = (const float*)d_in[34]; tw.gb0 = (const float*)d_in[35];
  tw.gw1 = (const float*)d_in[36]; tw.gb1 = (const float*)d_in[37];
  k_final<<<NV, 128, 0, stream>>>(outsv, tw, (float*)d_out);
}

// Round 14
// 971.353 us; speedup vs baseline: 2.6071x; 1.0146x over previous
//
#include <hip/hip_runtime.h>

#define NN   32768
#define NV   64
#define E0E  524288
#define HID  128
#define NL   4
#define NH   8
#define DH   16
#define SCALE 0.25f
#define PST  640   // P row stride: [q | k0 | v0 | k1 | v1]
#define LDA  136   // bf16 row stride for staged A (16B-aligned frag reads)

typedef __attribute__((ext_vector_type(8))) short short8;   // 8 bf16 = 4 VGPRs
typedef __attribute__((ext_vector_type(4))) float f32x4;

__device__ __forceinline__ float gelu_f(float x) {
  return 0.5f * x * (1.0f + erff(x * 0.7071067811865475f));
}
__device__ __forceinline__ float sigmoid_f(float x) {
  return 1.0f / (1.0f + __expf(-x));
}
__device__ __forceinline__ unsigned short f2bf(float x) {   // RN-even f32->bf16
  unsigned u = __float_as_uint(x);
  return (unsigned short)((u + 0x7FFFu + ((u >> 16) & 1u)) >> 16);
}
__device__ __forceinline__ float bf2f(unsigned short h) {
  return __uint_as_float(((unsigned)h) << 16);
}

union SMu {
  struct { unsigned short Ah[64][LDA]; unsigned short Al[64][LDA]; } a;  // 34816 B
  struct { float xr[HID]; float xn[HID]; } v;
};

// ---- stage 64xK=128 fp32 tile into split hi/lo bf16 LDS (coalesced float4 reads) ----
__device__ __forceinline__ void stage_A(unsigned short Ah[][LDA], unsigned short Al[][LDA],
                                        int t, const float* __restrict__ A, int m0, int gelu) {
  #pragma unroll
  for (int i = 0; i < 8; ++i) {
    int idx = t + 256 * i;            // float4 index over 64x32
    int m = idx >> 5, c4 = (idx & 31) * 4;
    float4 v = *(const float4*)(A + (size_t)(m0 + m) * HID + c4);
    if (gelu) { v.x = gelu_f(v.x); v.y = gelu_f(v.y); v.z = gelu_f(v.z); v.w = gelu_f(v.w); }
    unsigned short h0 = f2bf(v.x), h1 = f2bf(v.y), h2 = f2bf(v.z), h3 = f2bf(v.w);
    *(ushort4*)&Ah[m][c4] = make_ushort4(h0, h1, h2, h3);
    *(ushort4*)&Al[m][c4] = make_ushort4(f2bf(v.x - bf2f(h0)), f2bf(v.y - bf2f(h1)),
                                         f2bf(v.z - bf2f(h2)), f2bf(v.w - bf2f(h3)));
  }
}

// ---- MFMA split-bf16 GEMM: 64x128 tile, K=128. Wf = frag-ordered weights (hi plane,
// then lo plane at +16384). 4 waves, each: 16-row m-strip x 8 n-tiles of 16. ----
__device__ __forceinline__ void mfma_compute(const unsigned short Ah[][LDA],
    const unsigned short Al[][LDA], int t, const unsigned short* __restrict__ Wf,
    const float* __restrict__ bias, float* __restrict__ out, int ldo, int cbase, int m0,
    const float* __restrict__ skipv, const float* __restrict__ skipsrc) {
  const int w = t >> 6, lane = t & 63, c16 = lane & 15, quad = lane >> 4;
  f32x4 acc[8] = {};
  #pragma unroll
  for (int ks = 0; ks < 4; ++ks) {
    short8 ah = *(const short8*)&Ah[16 * w + c16][ks * 32 + quad * 8];
    short8 al = *(const short8*)&Al[16 * w + c16][ks * 32 + quad * 8];
    #pragma unroll
    for (int nt = 0; nt < 8; ++nt) {
      const unsigned short* bp = Wf + (size_t)((nt * 4 + ks) * 64 + lane) * 8;
      short8 bh = *(const short8*)bp;
      short8 bl = *(const short8*)(bp + 16384);
      acc[nt] = __builtin_amdgcn_mfma_f32_16x16x32_bf16(ah, bh, acc[nt], 0, 0, 0);
      acc[nt] = __builtin_amdgcn_mfma_f32_16x16x32_bf16(ah, bl, acc[nt], 0, 0, 0);
      acc[nt] = __builtin_amdgcn_mfma_f32_16x16x32_bf16(al, bh, acc[nt], 0, 0, 0);
    }
  }
  float g = 0.f, gm1 = 0.f;
  if (skipv) { g = sigmoid_f(*skipv); gm1 = 1.0f - g; }
  #pragma unroll
  for (int nt = 0; nt < 8; ++nt) {
    int col = cbase + nt * 16 + c16;
    float bb = bias[nt * 16 + c16];
    #pragma unroll
    for (int r = 0; r < 4; ++r) {
      int m = m0 + 16 * w + quad * 4 + r;   // C/D: row = quad*4 + reg, col = lane&15
      float v = acc[nt][r] + bb;
      if (skipv) v = g * v + gm1 * skipsrc[(size_t)m * ldo + col];
      out[(size_t)m * ldo + col] = v;
    }
  }
}

// ================= setup: zero counters + weight-combine (natural [n][k]) =====================
__global__ __launch_bounds__(256) void k_setup(
    int* __restrict__ cur0, int* __restrict__ cur1,
    const float* __restrict__ Wk, const float* __restrict__ Wv,
    const float* __restrict__ bk, const float* __restrict__ bv,
    const float* __restrict__ a_rel, const float* __restrict__ m_rel,
    const float* __restrict__ p_rel,
    float* __restrict__ CW, float* __restrict__ CB) {
  int b = blockIdx.x, t = threadIdx.x;
  if (b < 128) { int i = b * 256 + t; cur0[i] = 0; if (i < NV) cur1[i] = 0; return; }
  b -= 128;
  {
    int blk = b;                   // 0..15
    int l = blk >> 2, mat = blk & 3;
    int rel = mat >> 1;
    int isK = ((mat & 1) == 0);
    const float* W  = (isK ? Wk : Wv) + (size_t)(l * 2) * HID * HID;
    const float* bb = (isK ? bk : bv) + (l * 2) * HID;
    const float* R  = (isK ? a_rel : m_rel) + (size_t)((l * 2 + rel) * NH) * DH * DH;
    float* cw = CW + (size_t)blk * HID * HID;
    float* cb = CB + blk * HID;
    for (int o = t; o < HID * HID; o += 256) {
      int j = o >> 7, c = o & 127;
      int h = j >> 4, e = j & 15;
      float sc = isK ? (p_rel[(l * 2 + rel) * NH + h] * SCALE) : 1.0f;
      float s = 0.f;
      #pragma unroll
      for (int d = 0; d < DH; ++d)
        s += W[(size_t)(h * DH + d) * HID + c] * R[h * 256 + d * 16 + e];
      cw[(size_t)j * HID + c] = s * sc;   // [n][k]
    }
    if (t < HID) {
      int j = t, h = j >> 4, e = j & 15;
      float sc = isK ? (p_rel[(l * 2 + rel) * NH + h] * SCALE) : 1.0f;
      float s = 0.f;
      #pragma unroll
      for (int d = 0; d < DH; ++d) s += bb[h * DH + d] * R[h * 256 + d * 16 + e];
      cb[j] = s * sc;
    }
  }
}

// ================= frag-order + split all 24 weight mats (CW 0-15, Wq0 16-19, Wa0 20-23) ======
__global__ __launch_bounds__(256) void k_frag(const float* __restrict__ CW,
                                              const float* __restrict__ Wq,
                                              const float* __restrict__ Wa,
                                              unsigned short* __restrict__ FW) {
  int m = blockIdx.x, t = threadIdx.x;
  const float* src = (m < 16) ? (CW + (size_t)m * HID * HID)
                   : (m < 20) ? (Wq + (size_t)((m - 16) * 2) * HID * HID)
                              : (Wa + (size_t)((m - 20) * 2) * HID * HID);
  unsigned short* hi = FW + (size_t)m * 32768;
  unsigned short* lo = hi + 16384;
  for (int idx = t; idx < 16384; idx += 256) {
    int j = idx & 7, lane = (idx >> 3) & 63, ks = (idx >> 9) & 3, nt = idx >> 11;
    int n = nt * 16 + (lane & 15);
    int k = ks * 32 + (lane >> 4) * 8 + j;
    float x = src[(size_t)n * HID + k];
    unsigned short h = f2bf(x);
    hi[idx] = h;
    lo[idx] = f2bf(x - bf2f(h));
  }
}

// ================= histograms (4 edges/thread) ================================================
__global__ __launch_bounds__(256) void k_hist2(const int* __restrict__ dst0,
                                               const int* __restrict__ dst1,
                                               int* __restrict__ cur0, int* __restrict__ cur1) {
  int b = blockIdx.x, t = threadIdx.x;
  if (b < E0E / 1024) {
    int base = b * 1024 + t;
    #pragma unroll
    for (int i = 0; i < 4; ++i) atomicAdd(&cur0[dst0[base + i * 256]], 1);
  } else {
    int base = (b - E0E / 1024) * 1024 + t;
    #pragma unroll
    for (int i = 0; i < 4; ++i) atomicAdd(&cur1[dst1[base + i * 256]], 1);
  }
}

// ================= scans ======================================================================
__global__ __launch_bounds__(1024) void k_scan2(int* __restrict__ cnt0, int* __restrict__ rp0,
                                                int* __restrict__ cnt1, int* __restrict__ rp1) {
  __shared__ int sd[1024];
  int t = threadIdx.x;
  if (blockIdx.x == 0) {
    int loc[32];
    int base = t * 32, s = 0;
    #pragma unroll
    for (int i = 0; i < 32; ++i) { loc[i] = cnt0[base + i]; s += loc[i]; }
    sd[t] = s;
    __syncthreads();
    for (int off = 1; off < 1024; off <<= 1) {
      int v = (t >= off) ? sd[t - off] : 0;
      __syncthreads();
      sd[t] += v;
      __syncthreads();
    }
    int run = sd[t] - s;
    #pragma unroll
    for (int i = 0; i < 32; ++i) { rp0[base + i] = run; cnt0[base + i] = run; run += loc[i]; }
    if (t == 1023) rp0[NN] = E0E;
  } else if (t < 64) {
    int v = cnt1[t];
    int s = v;
    #pragma unroll
    for (int off = 1; off < 64; off <<= 1) {
      int u = __shfl_up(s, off);
      if (t >= off) s += u;
    }
    int ex = s - v;
    rp1[t] = ex; cnt1[t] = ex;
    if (t == 63) rp1[NV] = NN;
  }
}

// ================= scatters (4 edges/thread) ==================================================
__global__ __launch_bounds__(256) void k_scat2(const int* __restrict__ src0,
                                               const int* __restrict__ dst0,
                                               int* __restrict__ cur0, int* __restrict__ col0,
                                               const int* __restrict__ src1,
                                               const int* __restrict__ dst1,
                                               int* __restrict__ cur1, int* __restrict__ col1) {
  int b = blockIdx.x, t = threadIdx.x;
  if (b < E0E / 1024) {
    int base = b * 1024 + t;
    #pragma unroll
    for (int i = 0; i < 4; ++i) {
      int e = base + i * 256;
      int pos = atomicAdd(&cur0[dst0[e]], 1);
      col0[pos] = src0[e];
    }
  } else {
    int base = (b - E0E / 1024) * 1024 + t;
    #pragma unroll
    for (int i = 0; i < 4; ++i) {
      int e = base + i * 256;
      int pos = atomicAdd(&cur1[dst1[e]], 1);
      col1[pos] = src1[e];
    }
  }
}

// ================= k_mproj: one (m-tile, weight-slice) per block — grid (NN/64, 5) ============
// r13 lesson: fusing all 5 slices per block shrank grid to 2.25 blocks/CU -> 21% occupancy,
// MfmaUtil 8.5%. One slice per block gives 2560 blocks = 10/CU for latency hiding.
__launch_bounds__(256)
__global__ void k_mproj(const float* __restrict__ A, const unsigned short* __restrict__ WqF,
                        const unsigned short* __restrict__ CWF,
                        const float* __restrict__ bq0, const float* __restrict__ CB,
                        float* __restrict__ P) {
  __shared__ SMu sm;
  const int t = threadIdx.x;
  const int m0 = blockIdx.x * 64;
  const int y = blockIdx.y;
  stage_A(sm.a.Ah, sm.a.Al, t, A, m0, 0);
  __syncthreads();
  const unsigned short* Wf = (y == 0) ? WqF : (CWF + (size_t)(y - 1) * 32768);
  const float* bias = (y == 0) ? bq0 : (CB + (y - 1) * HID);
  mfma_compute(sm.a.Ah, sm.a.Al, t, Wf, bias, P, PST, y * HID, m0, nullptr, nullptr);
}

// ================= k_edges: edge0 (blocks < NN/4) + edge1 (NN/4 .. +512) — r8 best form =======
__launch_bounds__(256)
__global__ void k_edges(const float* __restrict__ P, const int* __restrict__ rowptr0,
                        const int* __restrict__ col0, float* __restrict__ agg,
                        const float* __restrict__ qv, const int* __restrict__ rowptr1,
                        const int* __restrict__ col1, float* __restrict__ part) {
  int lane = threadIdx.x & 63;
  if (blockIdx.x < NN / 4) {
    int n = blockIdx.x * 4 + (threadIdx.x >> 6);
    float2 q = *(const float2*)(P + (size_t)n * PST + 2 * lane);
    int e0 = rowptr0[n], e1 = rowptr0[n + 1];
    float acc0 = 0.f, acc1 = 0.f, wsum = 0.f;
    int e = e0;
    for (; e + 8 <= e1; e += 8) {
      const float* r[8];
      #pragma unroll
      for (int u = 0; u < 8; ++u) r[u] = P + (size_t)col0[e + u] * PST + 2 * lane;
      float2 kx[8], vx[8];
      #pragma unroll
      for (int u = 0; u < 8; ++u) kx[u] = *(const float2*)(r[u] + 128);
      #pragma unroll
      for (int u = 0; u < 8; ++u) vx[u] = *(const float2*)(r[u] + 256);
      float p[8];
      #pragma unroll
      for (int u = 0; u < 8; ++u) p[u] = q.x * kx[u].x + q.y * kx[u].y;
      #pragma unroll
      for (int u = 0; u < 8; ++u) {
        p[u] += __shfl_xor(p[u], 1); p[u] += __shfl_xor(p[u], 2); p[u] += __shfl_xor(p[u], 4);
      }
      #pragma unroll
      for (int u = 0; u < 8; ++u) {
        float w = __expf(p[u]);
        wsum += w; acc0 += w * vx[u].x; acc1 += w * vx[u].y;
      }
    }
    for (; e < e1; ++e) {
      const float* row = P + (size_t)col0[e] * PST + 2 * lane;
      float2 kv = *(const float2*)(row + 128);
      float p = q.x * kv.x + q.y * kv.y;
      p += __shfl_xor(p, 1); p += __shfl_xor(p, 2); p += __shfl_xor(p, 4);
      float w = __expf(p);
      float2 vv = *(const float2*)(row + 256);
      wsum += w; acc0 += w * vv.x; acc1 += w * vv.y;
    }
    float inv = 1.0f / (wsum + 1e-16f);
    *(float2*)(agg + (size_t)n * HID + 2 * lane) = make_float2(acc0 * inv, acc1 * inv);
  } else {
    int b2 = blockIdx.x - NN / 4;
    int g = b2 >> 3, ch = b2 & 7;
    int w = threadIdx.x >> 6;
    int slot = ch * 4 + w;
    float2 q = *(const float2*)(qv + g * HID + 2 * lane);
    int e0 = rowptr1[g], e1 = rowptr1[g + 1];
    int tot = e1 - e0;
    int len = (tot + 31) >> 5;
    int s0 = e0 + slot * len;
    int s1 = s0 + len; if (s1 > e1) s1 = e1;
    float acc0 = 0.f, acc1 = 0.f, wsum = 0.f;
    int e = s0;
    for (; e + 4 <= s1; e += 4) {
      const float* ra = P + (size_t)col1[e]     * PST + 2 * lane;
      const float* rb = P + (size_t)col1[e + 1] * PST + 2 * lane;
      const float* rc = P + (size_t)col1[e + 2] * PST + 2 * lane;
      const float* rd = P + (size_t)col1[e + 3] * PST + 2 * lane;
      float2 ka = *(const float2*)(ra + 384);
      float2 kb = *(const float2*)(rb + 384);
      float2 kc = *(const float2*)(rc + 384);
      float2 kd = *(const float2*)(rd + 384);
      float2 va = *(const float2*)(ra + 512);
      float2 vb = *(const float2*)(rb + 512);
      float2 vc = *(const float2*)(rc + 512);
      float2 vd = *(const float2*)(rd + 512);
      float pa = q.x * ka.x + q.y * ka.y;
      float pb = q.x * kb.x + q.y * kb.y;
      float pc = q.x * kc.x + q.y * kc.y;
      float pd = q.x * kd.x + q.y * kd.y;
      pa += __shfl_xor(pa, 1); pb += __shfl_xor(pb, 1); pc += __shfl_xor(pc, 1); pd += __shfl_xor(pd, 1);
      pa += __shfl_xor(pa, 2); pb += __shfl_xor(pb, 2); pc += __shfl_xor(pc, 2); pd += __shfl_xor(pd, 2);
      pa += __shfl_xor(pa, 4); pb += __shfl_xor(pb, 4); pc += __shfl_xor(pc, 4); pd += __shfl_xor(pd, 4);
      float wa = __expf(pa), wb = __expf(pb), wc = __expf(pc), wd = __expf(pd);
      wsum += (wa + wb) + (wc + wd);
      acc0 += wa * va.x + wb * vb.x + wc * vc.x + wd * vd.x;
      acc1 += wa * va.y + wb * vb.y + wc * vc.y + wd * vd.y;
    }
    for (; e < s1; ++e) {
      const float* row = P + (size_t)col1[e] * PST + 2 * lane;
      float2 kv = *(const float2*)(row + 384);
      float p = q.x * kv.x + q.y * kv.y;
      p += __shfl_xor(p, 1); p += __shfl_xor(p, 2); p += __shfl_xor(p, 4);
      float ww = __expf(p);
      float2 vv = *(const float2*)(row + 512);
      wsum += ww; acc0 += ww * vv.x; acc1 += ww * vv.y;
    }
    float* pp = part + (size_t)(g * 32 + slot) * 192;
    pp[lane] = acc0; pp[64 + lane] = acc1; pp[128 + lane] = wsum;
  }
}

// ================= k_post: MFMA out-GEMM + skip (blocks<512) + vnode tail =====================
struct PArgs {
  const float *agg; const unsigned short *WaF_l; const float *ba_l0, *skip_l0, *xold;
  float *xop;
  const float *part, *Wa_l1, *ba_l1, *skip_l1, *xvold;
  float *xv, *outsv_l, *qv;
  const float *Wq_n1, *bq_n1;
  int do_qv;
};

__launch_bounds__(256)
__global__ void k_post(PArgs f) {
  __shared__ SMu sm;
  const int t = threadIdx.x;
  if (blockIdx.x >= NN / 64) {
    // ---- vnode tail: edge1red + gelu + Wa[l,1] + skip -> xv, outsv; then qv(l+1) ----
    int v = blockIdx.x - NN / 64;
    if (t < 64) {
      float a0 = 0.f, a1 = 0.f, ws2 = 0.f;
      for (int s = 0; s < 32; ++s) {
        const float* p = f.part + (size_t)(v * 32 + s) * 192;
        a0 += p[t]; a1 += p[64 + t]; ws2 += p[128 + t];
      }
      float inv = 1.0f / (ws2 + 1e-16f);
      sm.v.xr[2 * t]     = gelu_f(a0 * inv);
      sm.v.xr[2 * t + 1] = gelu_f(a1 * inv);
    }
    __syncthreads();
    if (t < HID) {
      float s = f.ba_l1[t];
      const float4* wr = (const float4*)(f.Wa_l1 + (size_t)t * HID);
      const float4* xx = (const float4*)sm.v.xr;
      #pragma unroll 8
      for (int c = 0; c < HID / 4; ++c) {
        float4 w4 = wr[c], x4 = xx[c];
        s += x4.x * w4.x + x4.y * w4.y + x4.z * w4.z + x4.w * w4.w;
      }
      float gg = sigmoid_f(*f.skip_l1);
      float nv2 = gg * s + (1.f - gg) * f.xvold[v * HID + t];
      f.xv[v * HID + t] = nv2;
      f.outsv_l[v * HID + t] = nv2;
      sm.v.xn[t] = nv2;
    }
    __syncthreads();
    if (f.do_qv && t < HID) {
      float s = f.bq_n1[t];
      const float4* wr = (const float4*)(f.Wq_n1 + (size_t)t * HID);
      const float4* xx = (const float4*)sm.v.xn;
      #pragma unroll 8
      for (int c = 0; c < HID / 4; ++c) {
        float4 w4 = wr[c], x4 = xx[c];
        s += x4.x * w4.x + x4.y * w4.y + x4.z * w4.z + x4.w * w4.w;
      }
      f.qv[v * HID + t] = s;
    }
    return;
  }
  const int m0 = blockIdx.x * 64;
  // post(l): xop = g*(gelu(agg)@Wa^T + ba) + (1-g)*xold
  stage_A(sm.a.Ah, sm.a.Al, t, f.agg, m0, 1);
  __syncthreads();
  mfma_compute(sm.a.Ah, sm.a.Al, t, f.WaF_l, f.ba_l0, f.xop, HID, 0, m0, f.skip_l0, f.xold);
}

// ================= JK attention + node/graph MLPs =============================================
struct TailW {
  const float *win, *bin, *wout, *bout;
  const float *nw0, *nb0, *nw1, *nb1, *nw2, *nb2, *nw3, *nb3, *nw4, *nb4, *nw5, *nb5, *nw6, *nb6;
  const float *gw0, *gb0, *gw1, *gb1;
};

__launch_bounds__(128)
__global__ void k_final(const float* __restrict__ outsv, TailW tw, float* __restrict__ outp) {
  __shared__ float xs[4][HID], qq[4][HID], kk[4][HID], vv[4][HID], oo[4][HID];
  __shared__ float att[NH][4][4];
  __shared__ float hb[HID], tb[64];
  int b = blockIdx.x, t = threadIdx.x;
  for (int l = 0; l < 4; ++l) xs[l][t] = outsv[(size_t)(l * NV + b) * HID + t];
  __syncthreads();
  for (int l = 0; l < 4; ++l) {
    float sq = tw.bin[t], sk = tw.bin[t + 128], sv = tw.bin[t + 256];
    const float* wq = tw.win + (size_t)t * HID;
    const float* wk = tw.win + (size_t)(t + 128) * HID;
    const float* wv = tw.win + (size_t)(t + 256) * HID;
    for (int c = 0; c < HID; ++c) {
      float x = xs[l][c];
      sq += x * wq[c]; sk += x * wk[c]; sv += x * wv[c];
    }
    qq[l][t] = sq; kk[l][t] = sk; vv[l][t] = sv;
  }
  __syncthreads();
  {
    int h = t >> 4, ql = (t >> 2) & 3, kl = t & 3;
    float s = 0.f;
    #pragma unroll
    for (int d = 0; d < DH; ++d) s += qq[ql][h * DH + d] * kk[kl][h * DH + d];
    att[h][ql][kl] = s * SCALE;
  }
  __syncthreads();
  if (t < 32) {
    int h = t >> 2, ql = t & 3;
    float m = att[h][ql][0];
    for (int k2 = 1; k2 < 4; ++k2) m = fmaxf(m, att[h][ql][k2]);
    float e[4], s = 0.f;
    for (int k2 = 0; k2 < 4; ++k2) { e[k2] = __expf(att[h][ql][k2] - m); s += e[k2]; }
    for (int k2 = 0; k2 < 4; ++k2) att[h][ql][k2] = e[k2] / s;
  }
  __syncthreads();
  {
    int h = t >> 4;
    #pragma unroll
    for (int ql = 0; ql < 4; ++ql) {
      float s = 0.f;
      #pragma unroll
      for (int kl = 0; kl < 4; ++kl) s += att[h][ql][kl] * vv[kl][t];
      oo[ql][t] = s;
    }
  }
  __syncthreads();
  {
    float s = 0.f;
    const float* wr = tw.wout + (size_t)t * HID;
    for (int l = 0; l < 4; ++l) {
      float ss = tw.bout[t];
      for (int c = 0; c < HID; ++c) ss += oo[l][c] * wr[c];
      s += ss;
    }
    hb[t] = s;
  }
  __syncthreads();
  if (t < 64) { float s = tw.nb0[t]; const float* wr = tw.nw0 + t * 128; for (int c = 0; c < 128; ++c) s += hb[c] * wr[c]; tb[t] = gelu_f(s); }
  __syncthreads();
  if (t < 32) { float s = tw.nb1[t]; const float* wr = tw.nw1 + t * 64;  for (int c = 0; c < 64;  ++c) s += tb[c] * wr[c]; hb[t] = gelu_f(s); }
  __syncthreads();
  if (t < 16) { float s = tw.nb2[t]; const float* wr = tw.nw2 + t * 32;  for (int c = 0; c < 32;  ++c) s += hb[c] * wr[c]; tb[t] = gelu_f(s); }
  __syncthreads();
  if (t < 8)  { float s = tw.nb3[t]; const float* wr = tw.nw3 + t * 16;  for (int c = 0; c < 16;  ++c) s += tb[c] * wr[c]; hb[t] = gelu_f(s); }
  __syncthreads();
  if (t < 4)  { float s = tw.nb4[t]; const float* wr = tw.nw4 + t * 8;   for (int c = 0; c < 8;   ++c) s += hb[c] * wr[c]; tb[t] = gelu_f(s); }
  __syncthreads();
  if (t < 2)  { float s = tw.nb5[t]; const float* wr = tw.nw5 + t * 4;   for (int c = 0; c < 4;   ++c) s += tb[c] * wr[c]; hb[t] = gelu_f(s); }
  __syncthreads();
  if (t == 0) {
    float s = hb[0] * tw.nw6[0] + hb[1] * tw.nw6[1] + tw.nb6[0];
    float g0 = gelu_f(s * tw.gw0[0] + tw.gb0[0]);
    float g1 = gelu_f(s * tw.gw0[1] + tw.gb0[1]);
    outp[b] = g0 * tw.gw1[0] + g1 * tw.gw1[1] + tw.gb1[0];
  }
}

// ================= host =======================================================================
extern "C" void kernel_launch(void* const* d_in, const int* in_sizes, int n_in,
                              void* d_out, int out_size, void* d_ws, size_t ws_size,
                              hipStream_t stream) {
  const float* x_op = (const float*)d_in[0];
  const float* x_v  = (const float*)d_in[1];
  const int*   ei0  = (const int*)d_in[2];
  const int*   ei1  = (const int*)d_in[3];
  const float* Wk   = (const float*)d_in[4];
  const float* Wq   = (const float*)d_in[5];
  const float* Wv   = (const float*)d_in[6];
  const float* Wa   = (const float*)d_in[7];
  const float* bk   = (const float*)d_in[8];
  const float* bq   = (const float*)d_in[9];
  const float* bv   = (const float*)d_in[10];
  const float* ba   = (const float*)d_in[11];
  const float* skip = (const float*)d_in[12];
  const float* a_rel = (const float*)d_in[13];
  const float* m_rel = (const float*)d_in[14];
  const float* p_rel = (const float*)d_in[15];
  (void)in_sizes; (void)n_in; (void)out_size; (void)ws_size;

  char* wsp = (char*)d_ws;
  size_t off = 0;
  auto alloc = [&](size_t bytes) -> void* {
    void* p = wsp + off;
    off += (bytes + 255) & ~(size_t)255;
    return p;
  };
  float* P     = (float*)alloc((size_t)NN * PST * 4);
  float* xop   = (float*)alloc((size_t)NN * HID * 4);
  float* agg   = (float*)alloc((size_t)NN * HID * 4);
  float* CW    = (float*)alloc((size_t)16 * HID * HID * 4);
  float* CB    = (float*)alloc((size_t)16 * HID * 4);
  unsigned short* FW = (unsigned short*)alloc((size_t)24 * 32768 * 2);  // 1.57 MB frag weights
  float* xv    = (float*)alloc((size_t)NV * HID * 4);
  float* qv    = (float*)alloc((size_t)NV * HID * 4);
  float* outsv = (float*)alloc((size_t)NL * NV * HID * 4);
  float* part  = (float*)alloc((size_t)NV * 32 * 192 * 4);
  int* rowptr0 = (int*)alloc((size_t)(NN + 1) * 4);
  int* cur0    = (int*)alloc((size_t)NN * 4);
  int* col0    = (int*)alloc((size_t)E0E * 4);
  int* rowptr1 = (int*)alloc((size_t)(NV + 1) * 4);
  int* cur1    = (int*)alloc((size_t)NV * 4);
  int* col1    = (int*)alloc((size_t)NN * 4);

  k_setup<<<144, 256, 0, stream>>>(cur0, cur1, Wk, Wv, bk, bv, a_rel, m_rel, p_rel, CW, CB);
  k_frag<<<24, 256, 0, stream>>>(CW, Wq, Wa, FW);
  k_hist2<<<E0E / 1024 + NN / 1024, 256, 0, stream>>>(ei0 + E0E, ei1 + NN, cur0, cur1);
  k_scan2<<<2, 1024, 0, stream>>>(cur0, rowptr0, cur1, rowptr1);
  k_scat2<<<E0E / 1024 + NN / 1024, 256, 0, stream>>>(ei0, ei0 + E0E, cur0, col0,
                                                      ei1, ei1 + NN, cur1, col1);

  // qv for layer 0 (piggyback on k_post's vnode-tail shape via a tiny standalone pass is
  // overkill: reuse k_mproj grid y=0..4 for P, qv0 done by a 64-block micro-kernel below)
  // Layer-0 projection straight from inputs (MFMA), one slice per block:
  k_mproj<<<dim3(NN / 64, 5), 256, 0, stream>>>(x_op, FW + (size_t)16 * 32768, FW, bq, CB, P);
  // qv0 = x_v @ Wq[0,1]^T + bq[0,1]  (64 rows) — fold into k_post's tail shape:
  {
    PArgs f0 = {};
    f0.part = part;               // unused rows guarded by do-nothing: use dedicated micro-launch
    // dedicated tiny kernel not worth it; compute qv0 via k_post tail with do_qv only:
    // simpler: small lambda-kernel below
    (void)f0;
  }
  // tiny qv0 kernel via k_post tail path would need part; use a micro grid of k_mproj? No:
  // dedicated micro-kernel:
  struct QV0 { const float *x, *W, *b; float* qv; };
  // (declared below as k_qv0)
  extern __global__ void k_qv0(const float*, const float*, const float*, float*);
  k_qv0<<<NV, 128, 0, stream>>>(x_v, Wq + (size_t)1 * HID * HID, bq + HID, qv);

  for (int l = 0; l < NL; ++l) {
    k_edges<<<NN / 4 + NV * 8, 256, 0, stream>>>(P, rowptr0, col0, agg, qv, rowptr1, col1, part);
    PArgs f;
    f.agg = agg;
    f.WaF_l = FW + (size_t)(20 + l) * 32768;
    f.ba_l0 = ba + (l * 2 + 0) * HID;
    f.skip_l0 = skip + l * 2 + 0;
    f.xold = (l == 0) ? x_op : xop;
    f.xop = xop;
    f.part = part;
    f.Wa_l1 = Wa + (size_t)(l * 2 + 1) * HID * HID;
    f.ba_l1 = ba + (l * 2 + 1) * HID;
    f.skip_l1 = skip + l * 2 + 1;
    f.xvold = (l == 0) ? x_v : xv;
    f.xv = xv;
    f.outsv_l = outsv + (size_t)l * NV * HID;
    f.qv = qv;
    int ln = (l + 1) & 3;
    f.Wq_n1 = Wq + (size_t)(ln * 2 + 1) * HID * HID;
    f.bq_n1 = bq + (ln * 2 + 1) * HID;
    f.do_qv = (l < NL - 1) ? 1 : 0;
    k_post<<<NN / 64 + NV, 256, 0, stream>>>(f);
    if (l < NL - 1) {
      k_mproj<<<dim3(NN / 64, 5), 256, 0, stream>>>(xop, FW + (size_t)(16 + ln) * 32768,
                                                    FW + (size_t)(ln * 4) * 32768,
                                                    bq + (ln * 2 + 0) * HID,
                                                    CB + ln * 4 * HID, P);
    }
  }

  TailW tw;
  tw.win  = (const float*)d_in[16]; tw.bin  = (const float*)d_in[17];
  tw.wout = (const float*)d_in[18]; tw.bout = (const float*)d_in[19];
  tw.nw0 = (const float*)d_in[20]; tw.nb0 = (const float*)d_in[21];
  tw.nw1 = (const float*)d_in[22]; tw.nb1 = (const float*)d_in[23];
  tw.nw2 = (const float*)d_in[24]; tw.nb2 = (const float*)d_in[25];
  tw.nw3 = (const float*)d_in[26]; tw.nb3 = (const float*)d_in[27];
  tw.nw4 = (const float*)d_in[28]; tw.nb4 = (const float*)d_in[29];
  tw.nw5 = (const float*)d_in[30]; tw.nb5 = (const float*)d_in[31];
  tw.nw6 = (const float*)d_in[32]; tw.nb6 = (const float*)d_in[33];
  tw.gw0 = (const float*)d_in[34]; tw.gb0 = (const float*)d_in[35];
  tw.gw1 = (const float*)d_in[36]; tw.gb1 = (const float*)d_in[37];
  k_final<<<NV, 128, 0, stream>>>(outsv, tw, (float*)d_out);
}

// ================= qv0: 64 rows, qv = x @ W^T + b =============================================
__global__ __launch_bounds__(128) void k_qv0(const float* __restrict__ X,
                                             const float* __restrict__ W,
                                             const float* __restrict__ bias,
                                             float* __restrict__ out) {
  __shared__ float xr[HID];
  int n = blockIdx.x, t = threadIdx.x;
  xr[t] = X[n * HID + t];
  __syncthreads();
  float s = bias[t];
  const float4* wr = (const float4*)(W + (size_t)t * HID);
  const float4* xx = (const float4*)xr;
  #pragma unroll 8
  for (int c = 0; c < HID / 4; ++c) {
    float4 w4 = wr[c], x4 = xx[c];
    s += x4.x * w4.x + x4.y * w4.y + x4.z * w4.z + x4.w * w4.w;
  }
  out[n * HID + t] = s;
}

// Round 15
// 851.278 us; speedup vs baseline: 2.9748x; 1.1411x over previous
//
#include <hip/hip_runtime.h>

#define NN   32768
#define NV   64
#define E0E  524288
#define HID  128
#define NL   4
#define NH   8
#define DH   16
#define SCALE 0.25f
#define PST  640   // P row stride: [q | k0 | v0 | k1 | v1]
#define LDA  136   // bf16 row stride for staged A (16B-aligned frag reads, 2-way bank alias)

typedef __attribute__((ext_vector_type(8))) short short8;   // 8 bf16 = 4 VGPRs
typedef __attribute__((ext_vector_type(4))) float f32x4;

__device__ __forceinline__ float gelu_f(float x) {
  return 0.5f * x * (1.0f + erff(x * 0.7071067811865475f));
}
__device__ __forceinline__ float sigmoid_f(float x) {
  return 1.0f / (1.0f + __expf(-x));
}
__device__ __forceinline__ unsigned short f2bf(float x) {   // RN-even f32->bf16
  unsigned u = __float_as_uint(x);
  return (unsigned short)((u + 0x7FFFu + ((u >> 16) & 1u)) >> 16);
}
__device__ __forceinline__ float bf2f(unsigned short h) {
  return __uint_as_float(((unsigned)h) << 16);
}

union SMu {
  struct { unsigned short Ah[64][LDA]; unsigned short Al[64][LDA]; } a;  // 34816 B
  struct { float xr[HID]; float xn[HID]; } v;
};

// ---- stage 64xK=128 fp32 tile into split hi/lo bf16 LDS (coalesced float4 reads) ----
__device__ __forceinline__ void stage_A(unsigned short Ah[][LDA], unsigned short Al[][LDA],
                                        int t, const float* __restrict__ A, int m0, int gelu) {
  #pragma unroll
  for (int i = 0; i < 8; ++i) {
    int idx = t + 256 * i;            // float4 index over 64x32
    int m = idx >> 5, c4 = (idx & 31) * 4;
    float4 v = *(const float4*)(A + (size_t)(m0 + m) * HID + c4);
    if (gelu) { v.x = gelu_f(v.x); v.y = gelu_f(v.y); v.z = gelu_f(v.z); v.w = gelu_f(v.w); }
    unsigned short h0 = f2bf(v.x), h1 = f2bf(v.y), h2 = f2bf(v.z), h3 = f2bf(v.w);
    *(ushort4*)&Ah[m][c4] = make_ushort4(h0, h1, h2, h3);
    *(ushort4*)&Al[m][c4] = make_ushort4(f2bf(v.x - bf2f(h0)), f2bf(v.y - bf2f(h1)),
                                         f2bf(v.z - bf2f(h2)), f2bf(v.w - bf2f(h3)));
  }
}

// ---- MFMA split-bf16 GEMM: 64x128 tile, K=128, B-reuse form ----
// r14 lesson: wave=1 m-strip x 8 nt meant 64 one-use L2 B-loads/wave (4x redundant across
// waves) -> MfmaUtil 8.5%. Now wave w owns nt {2w, 2w+1} x all 4 m-strips: 16 B-loads/wave,
// each feeding 12 MFMAs; block reads the 64KB slice exactly once.
__device__ __forceinline__ void mfma_compute(const unsigned short Ah[][LDA],
    const unsigned short Al[][LDA], int t, const unsigned short* __restrict__ Wf,
    const float* __restrict__ bias, float* __restrict__ out, int ldo, int cbase, int m0,
    const float* __restrict__ skipv, const float* __restrict__ skipsrc) {
  const int w = t >> 6, lane = t & 63, c16 = lane & 15, quad = lane >> 4;
  f32x4 acc[2][4] = {};
  #pragma unroll
  for (int ks = 0; ks < 4; ++ks) {
    short8 ah[4], al[4];
    #pragma unroll
    for (int s = 0; s < 4; ++s) {
      ah[s] = *(const short8*)&Ah[16 * s + c16][ks * 32 + quad * 8];
      al[s] = *(const short8*)&Al[16 * s + c16][ks * 32 + quad * 8];
    }
    #pragma unroll
    for (int j = 0; j < 2; ++j) {
      const int nt = 2 * w + j;
      const unsigned short* bp = Wf + (size_t)((nt * 4 + ks) * 64 + lane) * 8;
      short8 bh = *(const short8*)bp;
      short8 bl = *(const short8*)(bp + 16384);
      #pragma unroll
      for (int s = 0; s < 4; ++s) {
        acc[j][s] = __builtin_amdgcn_mfma_f32_16x16x32_bf16(ah[s], bh, acc[j][s], 0, 0, 0);
        acc[j][s] = __builtin_amdgcn_mfma_f32_16x16x32_bf16(ah[s], bl, acc[j][s], 0, 0, 0);
        acc[j][s] = __builtin_amdgcn_mfma_f32_16x16x32_bf16(al[s], bh, acc[j][s], 0, 0, 0);
      }
    }
  }
  float g = 0.f, gm1 = 0.f;
  if (skipv) { g = sigmoid_f(*skipv); gm1 = 1.0f - g; }
  #pragma unroll
  for (int j = 0; j < 2; ++j) {
    const int nt = 2 * w + j;
    const int col = cbase + nt * 16 + c16;
    const float bb = bias[nt * 16 + c16];
    #pragma unroll
    for (int s = 0; s < 4; ++s) {
      #pragma unroll
      for (int r = 0; r < 4; ++r) {
        int m = m0 + 16 * s + quad * 4 + r;   // C/D: row = quad*4 + reg, col = lane&15
        float v = acc[j][s][r] + bb;
        if (skipv) v = g * v + gm1 * skipsrc[(size_t)m * ldo + col];
        out[(size_t)m * ldo + col] = v;
      }
    }
  }
}

// ================= setup: zero counters + weight-combine (natural [n][k]) =====================
__global__ __launch_bounds__(256) void k_setup(
    int* __restrict__ cur0, int* __restrict__ cur1,
    const float* __restrict__ Wk, const float* __restrict__ Wv,
    const float* __restrict__ bk, const float* __restrict__ bv,
    const float* __restrict__ a_rel, const float* __restrict__ m_rel,
    const float* __restrict__ p_rel,
    float* __restrict__ CW, float* __restrict__ CB) {
  int b = blockIdx.x, t = threadIdx.x;
  if (b < 128) { int i = b * 256 + t; cur0[i] = 0; if (i < NV) cur1[i] = 0; return; }
  b -= 128;
  {
    int blk = b;                   // 0..15
    int l = blk >> 2, mat = blk & 3;
    int rel = mat >> 1;
    int isK = ((mat & 1) == 0);
    const float* W  = (isK ? Wk : Wv) + (size_t)(l * 2) * HID * HID;
    const float* bb = (isK ? bk : bv) + (l * 2) * HID;
    const float* R  = (isK ? a_rel : m_rel) + (size_t)((l * 2 + rel) * NH) * DH * DH;
    float* cw = CW + (size_t)blk * HID * HID;
    float* cb = CB + blk * HID;
    for (int o = t; o < HID * HID; o += 256) {
      int j = o >> 7, c = o & 127;
      int h = j >> 4, e = j & 15;
      float sc = isK ? (p_rel[(l * 2 + rel) * NH + h] * SCALE) : 1.0f;
      float s = 0.f;
      #pragma unroll
      for (int d = 0; d < DH; ++d)
        s += W[(size_t)(h * DH + d) * HID + c] * R[h * 256 + d * 16 + e];
      cw[(size_t)j * HID + c] = s * sc;   // [n][k]
    }
    if (t < HID) {
      int j = t, h = j >> 4, e = j & 15;
      float sc = isK ? (p_rel[(l * 2 + rel) * NH + h] * SCALE) : 1.0f;
      float s = 0.f;
      #pragma unroll
      for (int d = 0; d < DH; ++d) s += bb[h * DH + d] * R[h * 256 + d * 16 + e];
      cb[j] = s * sc;
    }
  }
}

// ================= frag-order + split all 24 weight mats (CW 0-15, Wq0 16-19, Wa0 20-23) ======
__global__ __launch_bounds__(256) void k_frag(const float* __restrict__ CW,
                                              const float* __restrict__ Wq,
                                              const float* __restrict__ Wa,
                                              unsigned short* __restrict__ FW) {
  int m = blockIdx.x, t = threadIdx.x;
  const float* src = (m < 16) ? (CW + (size_t)m * HID * HID)
                   : (m < 20) ? (Wq + (size_t)((m - 16) * 2) * HID * HID)
                              : (Wa + (size_t)((m - 20) * 2) * HID * HID);
  unsigned short* hi = FW + (size_t)m * 32768;
  unsigned short* lo = hi + 16384;
  for (int idx = t; idx < 16384; idx += 256) {
    int j = idx & 7, lane = (idx >> 3) & 63, ks = (idx >> 9) & 3, nt = idx >> 11;
    int n = nt * 16 + (lane & 15);
    int k = ks * 32 + (lane >> 4) * 8 + j;
    float x = src[(size_t)n * HID + k];
    unsigned short h = f2bf(x);
    hi[idx] = h;
    lo[idx] = f2bf(x - bf2f(h));
  }
}

// ================= histograms (4 edges/thread) ================================================
__global__ __launch_bounds__(256) void k_hist2(const int* __restrict__ dst0,
                                               const int* __restrict__ dst1,
                                               int* __restrict__ cur0, int* __restrict__ cur1) {
  int b = blockIdx.x, t = threadIdx.x;
  if (b < E0E / 1024) {
    int base = b * 1024 + t;
    #pragma unroll
    for (int i = 0; i < 4; ++i) atomicAdd(&cur0[dst0[base + i * 256]], 1);
  } else {
    int base = (b - E0E / 1024) * 1024 + t;
    #pragma unroll
    for (int i = 0; i < 4; ++i) atomicAdd(&cur1[dst1[base + i * 256]], 1);
  }
}

// ================= scans ======================================================================
__global__ __launch_bounds__(1024) void k_scan2(int* __restrict__ cnt0, int* __restrict__ rp0,
                                                int* __restrict__ cnt1, int* __restrict__ rp1) {
  __shared__ int sd[1024];
  int t = threadIdx.x;
  if (blockIdx.x == 0) {
    int loc[32];
    int base = t * 32, s = 0;
    #pragma unroll
    for (int i = 0; i < 32; ++i) { loc[i] = cnt0[base + i]; s += loc[i]; }
    sd[t] = s;
    __syncthreads();
    for (int off = 1; off < 1024; off <<= 1) {
      int v = (t >= off) ? sd[t - off] : 0;
      __syncthreads();
      sd[t] += v;
      __syncthreads();
    }
    int run = sd[t] - s;
    #pragma unroll
    for (int i = 0; i < 32; ++i) { rp0[base + i] = run; cnt0[base + i] = run; run += loc[i]; }
    if (t == 1023) rp0[NN] = E0E;
  } else if (t < 64) {
    int v = cnt1[t];
    int s = v;
    #pragma unroll
    for (int off = 1; off < 64; off <<= 1) {
      int u = __shfl_up(s, off);
      if (t >= off) s += u;
    }
    int ex = s - v;
    rp1[t] = ex; cnt1[t] = ex;
    if (t == 63) rp1[NV] = NN;
  }
}

// ================= scatters (4 edges/thread) ==================================================
__global__ __launch_bounds__(256) void k_scat2(const int* __restrict__ src0,
                                               const int* __restrict__ dst0,
                                               int* __restrict__ cur0, int* __restrict__ col0,
                                               const int* __restrict__ src1,
                                               const int* __restrict__ dst1,
                                               int* __restrict__ cur1, int* __restrict__ col1) {
  int b = blockIdx.x, t = threadIdx.x;
  if (b < E0E / 1024) {
    int base = b * 1024 + t;
    #pragma unroll
    for (int i = 0; i < 4; ++i) {
      int e = base + i * 256;
      int pos = atomicAdd(&cur0[dst0[e]], 1);
      col0[pos] = src0[e];
    }
  } else {
    int base = (b - E0E / 1024) * 1024 + t;
    #pragma unroll
    for (int i = 0; i < 4; ++i) {
      int e = base + i * 256;
      int pos = atomicAdd(&cur1[dst1[e]], 1);
      col1[pos] = src1[e];
    }
  }
}

// ================= k_qv0: 64 rows, qv = x @ W^T + b ===========================================
__global__ __launch_bounds__(128) void k_qv0(const float* __restrict__ X,
                                             const float* __restrict__ W,
                                             const float* __restrict__ bias,
                                             float* __restrict__ out) {
  __shared__ float xr[HID];
  int n = blockIdx.x, t = threadIdx.x;
  xr[t] = X[n * HID + t];
  __syncthreads();
  float s = bias[t];
  const float4* wr = (const float4*)(W + (size_t)t * HID);
  const float4* xx = (const float4*)xr;
  #pragma unroll 8
  for (int c = 0; c < HID / 4; ++c) {
    float4 w4 = wr[c], x4 = xx[c];
    s += x4.x * w4.x + x4.y * w4.y + x4.z * w4.z + x4.w * w4.w;
  }
  out[n * HID + t] = s;
}

// ================= k_mproj: one (m-tile, weight-slice) per block — grid (NN/64, 5) ============
__launch_bounds__(256)
__global__ void k_mproj(const float* __restrict__ A, const unsigned short* __restrict__ WqF,
                        const unsigned short* __restrict__ CWF,
                        const float* __restrict__ bq0, const float* __restrict__ CB,
                        float* __restrict__ P) {
  __shared__ SMu sm;
  const int t = threadIdx.x;
  const int m0 = blockIdx.x * 64;
  const int y = blockIdx.y;
  stage_A(sm.a.Ah, sm.a.Al, t, A, m0, 0);
  __syncthreads();
  const unsigned short* Wf = (y == 0) ? WqF : (CWF + (size_t)(y - 1) * 32768);
  const float* bias = (y == 0) ? bq0 : (CB + (y - 1) * HID);
  mfma_compute(sm.a.Ah, sm.a.Al, t, Wf, bias, P, PST, y * HID, m0, nullptr, nullptr);
}

// ================= k_edges: edge0 (blocks < NN/4) + edge1 (NN/4 .. +512) — r8 best form =======
__launch_bounds__(256)
__global__ void k_edges(const float* __restrict__ P, const int* __restrict__ rowptr0,
                        const int* __restrict__ col0, float* __restrict__ agg,
                        const float* __restrict__ qv, const int* __restrict__ rowptr1,
                        const int* __restrict__ col1, float* __restrict__ part) {
  int lane = threadIdx.x & 63;
  if (blockIdx.x < NN / 4) {
    int n = blockIdx.x * 4 + (threadIdx.x >> 6);
    float2 q = *(const float2*)(P + (size_t)n * PST + 2 * lane);
    int e0 = rowptr0[n], e1 = rowptr0[n + 1];
    float acc0 = 0.f, acc1 = 0.f, wsum = 0.f;
    int e = e0;
    for (; e + 8 <= e1; e += 8) {
      const float* r[8];
      #pragma unroll
      for (int u = 0; u < 8; ++u) r[u] = P + (size_t)col0[e + u] * PST + 2 * lane;
      float2 kx[8], vx[8];
      #pragma unroll
      for (int u = 0; u < 8; ++u) kx[u] = *(const float2*)(r[u] + 128);
      #pragma unroll
      for (int u = 0; u < 8; ++u) vx[u] = *(const float2*)(r[u] + 256);
      float p[8];
      #pragma unroll
      for (int u = 0; u < 8; ++u) p[u] = q.x * kx[u].x + q.y * kx[u].y;
      #pragma unroll
      for (int u = 0; u < 8; ++u) {
        p[u] += __shfl_xor(p[u], 1); p[u] += __shfl_xor(p[u], 2); p[u] += __shfl_xor(p[u], 4);
      }
      #pragma unroll
      for (int u = 0; u < 8; ++u) {
        float w = __expf(p[u]);
        wsum += w; acc0 += w * vx[u].x; acc1 += w * vx[u].y;
      }
    }
    for (; e < e1; ++e) {
      const float* row = P + (size_t)col0[e] * PST + 2 * lane;
      float2 kv = *(const float2*)(row + 128);
      float p = q.x * kv.x + q.y * kv.y;
      p += __shfl_xor(p, 1); p += __shfl_xor(p, 2); p += __shfl_xor(p, 4);
      float w = __expf(p);
      float2 vv = *(const float2*)(row + 256);
      wsum += w; acc0 += w * vv.x; acc1 += w * vv.y;
    }
    float inv = 1.0f / (wsum + 1e-16f);
    *(float2*)(agg + (size_t)n * HID + 2 * lane) = make_float2(acc0 * inv, acc1 * inv);
  } else {
    int b2 = blockIdx.x - NN / 4;
    int g = b2 >> 3, ch = b2 & 7;
    int w = threadIdx.x >> 6;
    int slot = ch * 4 + w;
    float2 q = *(const float2*)(qv + g * HID + 2 * lane);
    int e0 = rowptr1[g], e1 = rowptr1[g + 1];
    int tot = e1 - e0;
    int len = (tot + 31) >> 5;
    int s0 = e0 + slot * len;
    int s1 = s0 + len; if (s1 > e1) s1 = e1;
    float acc0 = 0.f, acc1 = 0.f, wsum = 0.f;
    int e = s0;
    for (; e + 4 <= s1; e += 4) {
      const float* ra = P + (size_t)col1[e]     * PST + 2 * lane;
      const float* rb = P + (size_t)col1[e + 1] * PST + 2 * lane;
      const float* rc = P + (size_t)col1[e + 2] * PST + 2 * lane;
      const float* rd = P + (size_t)col1[e + 3] * PST + 2 * lane;
      float2 ka = *(const float2*)(ra + 384);
      float2 kb = *(const float2*)(rb + 384);
      float2 kc = *(const float2*)(rc + 384);
      float2 kd = *(const float2*)(rd + 384);
      float2 va = *(const float2*)(ra + 512);
      float2 vb = *(const float2*)(rb + 512);
      float2 vc = *(const float2*)(rc + 512);
      float2 vd = *(const float2*)(rd + 512);
      float pa = q.x * ka.x + q.y * ka.y;
      float pb = q.x * kb.x + q.y * kb.y;
      float pc = q.x * kc.x + q.y * kc.y;
      float pd = q.x * kd.x + q.y * kd.y;
      pa += __shfl_xor(pa, 1); pb += __shfl_xor(pb, 1); pc += __shfl_xor(pc, 1); pd += __shfl_xor(pd, 1);
      pa += __shfl_xor(pa, 2); pb += __shfl_xor(pb, 2); pc += __shfl_xor(pc, 2); pd += __shfl_xor(pd, 2);
      pa += __shfl_xor(pa, 4); pb += __shfl_xor(pb, 4); pc += __shfl_xor(pc, 4); pd += __shfl_xor(pd, 4);
      float wa = __expf(pa), wb = __expf(pb), wc = __expf(pc), wd = __expf(pd);
      wsum += (wa + wb) + (wc + wd);
      acc0 += wa * va.x + wb * vb.x + wc * vc.x + wd * vd.x;
      acc1 += wa * va.y + wb * vb.y + wc * vc.y + wd * vd.y;
    }
    for (; e < s1; ++e) {
      const float* row = P + (size_t)col1[e] * PST + 2 * lane;
      float2 kv = *(const float2*)(row + 384);
      float p = q.x * kv.x + q.y * kv.y;
      p += __shfl_xor(p, 1); p += __shfl_xor(p, 2); p += __shfl_xor(p, 4);
      float ww = __expf(p);
      float2 vv = *(const float2*)(row + 512);
      wsum += ww; acc0 += ww * vv.x; acc1 += ww * vv.y;
    }
    float* pp = part + (size_t)(g * 32 + slot) * 192;
    pp[lane] = acc0; pp[64 + lane] = acc1; pp[128 + lane] = wsum;
  }
}

// ================= k_post: MFMA out-GEMM + skip (blocks<512) + vnode tail =====================
struct PArgs {
  const float *agg; const unsigned short *WaF_l; const float *ba_l0, *skip_l0, *xold;
  float *xop;
  const float *part, *Wa_l1, *ba_l1, *skip_l1, *xvold;
  float *xv, *outsv_l, *qv;
  const float *Wq_n1, *bq_n1;
  int do_qv;
};

__launch_bounds__(256)
__global__ void k_post(PArgs f) {
  __shared__ SMu sm;
  const int t = threadIdx.x;
  if (blockIdx.x >= NN / 64) {
    // ---- vnode tail: edge1red + gelu + Wa[l,1] + skip -> xv, outsv; then qv(l+1) ----
    int v = blockIdx.x - NN / 64;
    if (t < 64) {
      float a0 = 0.f, a1 = 0.f, ws2 = 0.f;
      for (int s = 0; s < 32; ++s) {
        const float* p = f.part + (size_t)(v * 32 + s) * 192;
        a0 += p[t]; a1 += p[64 + t]; ws2 += p[128 + t];
      }
      float inv = 1.0f / (ws2 + 1e-16f);
      sm.v.xr[2 * t]     = gelu_f(a0 * inv);
      sm.v.xr[2 * t + 1] = gelu_f(a1 * inv);
    }
    __syncthreads();
    if (t < HID) {
      float s = f.ba_l1[t];
      const float4* wr = (const float4*)(f.Wa_l1 + (size_t)t * HID);
      const float4* xx = (const float4*)sm.v.xr;
      #pragma unroll 8
      for (int c = 0; c < HID / 4; ++c) {
        float4 w4 = wr[c], x4 = xx[c];
        s += x4.x * w4.x + x4.y * w4.y + x4.z * w4.z + x4.w * w4.w;
      }
      float gg = sigmoid_f(*f.skip_l1);
      float nv2 = gg * s + (1.f - gg) * f.xvold[v * HID + t];
      f.xv[v * HID + t] = nv2;
      f.outsv_l[v * HID + t] = nv2;
      sm.v.xn[t] = nv2;
    }
    __syncthreads();
    if (f.do_qv && t < HID) {
      float s = f.bq_n1[t];
      const float4* wr = (const float4*)(f.Wq_n1 + (size_t)t * HID);
      const float4* xx = (const float4*)sm.v.xn;
      #pragma unroll 8
      for (int c = 0; c < HID / 4; ++c) {
        float4 w4 = wr[c], x4 = xx[c];
        s += x4.x * w4.x + x4.y * w4.y + x4.z * w4.z + x4.w * w4.w;
      }
      f.qv[v * HID + t] = s;
    }
    return;
  }
  const int m0 = blockIdx.x * 64;
  // post(l): xop = g*(gelu(agg)@Wa^T + ba) + (1-g)*xold
  stage_A(sm.a.Ah, sm.a.Al, t, f.agg, m0, 1);
  __syncthreads();
  mfma_compute(sm.a.Ah, sm.a.Al, t, f.WaF_l, f.ba_l0, f.xop, HID, 0, m0, f.skip_l0, f.xold);
}

// ================= JK attention + node/graph MLPs =============================================
struct TailW {
  const float *win, *bin, *wout, *bout;
  const float *nw0, *nb0, *nw1, *nb1, *nw2, *nb2, *nw3, *nb3, *nw4, *nb4, *nw5, *nb5, *nw6, *nb6;
  const float *gw0, *gb0, *gw1, *gb1;
};

__launch_bounds__(128)
__global__ void k_final(const float* __restrict__ outsv, TailW tw, float* __restrict__ outp) {
  __shared__ float xs[4][HID], qq[4][HID], kk[4][HID], vv[4][HID], oo[4][HID];
  __shared__ float att[NH][4][4];
  __shared__ float hb[HID], tb[64];
  int b = blockIdx.x, t = threadIdx.x;
  for (int l = 0; l < 4; ++l) xs[l][t] = outsv[(size_t)(l * NV + b) * HID + t];
  __syncthreads();
  for (int l = 0; l < 4; ++l) {
    float sq = tw.bin[t], sk = tw.bin[t + 128], sv = tw.bin[t + 256];
    const float* wq = tw.win + (size_t)t * HID;
    const float* wk = tw.win + (size_t)(t + 128) * HID;
    const float* wv = tw.win + (size_t)(t + 256) * HID;
    for (int c = 0; c < HID; ++c) {
      float x = xs[l][c];
      sq += x * wq[c]; sk += x * wk[c]; sv += x * wv[c];
    }
    qq[l][t] = sq; kk[l][t] = sk; vv[l][t] = sv;
  }
  __syncthreads();
  {
    int h = t >> 4, ql = (t >> 2) & 3, kl = t & 3;
    float s = 0.f;
    #pragma unroll
    for (int d = 0; d < DH; ++d) s += qq[ql][h * DH + d] * kk[kl][h * DH + d];
    att[h][ql][kl] = s * SCALE;
  }
  __syncthreads();
  if (t < 32) {
    int h = t >> 2, ql = t & 3;
    float m = att[h][ql][0];
    for (int k2 = 1; k2 < 4; ++k2) m = fmaxf(m, att[h][ql][k2]);
    float e[4], s = 0.f;
    for (int k2 = 0; k2 < 4; ++k2) { e[k2] = __expf(att[h][ql][k2] - m); s += e[k2]; }
    for (int k2 = 0; k2 < 4; ++k2) att[h][ql][k2] = e[k2] / s;
  }
  __syncthreads();
  {
    int h = t >> 4;
    #pragma unroll
    for (int ql = 0; ql < 4; ++ql) {
      float s = 0.f;
      #pragma unroll
      for (int kl = 0; kl < 4; ++kl) s += att[h][ql][kl] * vv[kl][t];
      oo[ql][t] = s;
    }
  }
  __syncthreads();
  {
    float s = 0.f;
    const float* wr = tw.wout + (size_t)t * HID;
    for (int l = 0; l < 4; ++l) {
      float ss = tw.bout[t];
      for (int c = 0; c < HID; ++c) ss += oo[l][c] * wr[c];
      s += ss;
    }
    hb[t] = s;
  }
  __syncthreads();
  if (t < 64) { float s = tw.nb0[t]; const float* wr = tw.nw0 + t * 128; for (int c = 0; c < 128; ++c) s += hb[c] * wr[c]; tb[t] = gelu_f(s); }
  __syncthreads();
  if (t < 32) { float s = tw.nb1[t]; const float* wr = tw.nw1 + t * 64;  for (int c = 0; c < 64;  ++c) s += tb[c] * wr[c]; hb[t] = gelu_f(s); }
  __syncthreads();
  if (t < 16) { float s = tw.nb2[t]; const float* wr = tw.nw2 + t * 32;  for (int c = 0; c < 32;  ++c) s += hb[c] * wr[c]; tb[t] = gelu_f(s); }
  __syncthreads();
  if (t < 8)  { float s = tw.nb3[t]; const float* wr = tw.nw3 + t * 16;  for (int c = 0; c < 16;  ++c) s += tb[c] * wr[c]; hb[t] = gelu_f(s); }
  __syncthreads();
  if (t < 4)  { float s = tw.nb4[t]; const float* wr = tw.nw4 + t * 8;   for (int c = 0; c < 8;   ++c) s += hb[c] * wr[c]; tb[t] = gelu_f(s); }
  __syncthreads();
  if (t < 2)  { float s = tw.nb5[t]; const float* wr = tw.nw5 + t * 4;   for (int c = 0; c < 4;   ++c) s += tb[c] * wr[c]; hb[t] = gelu_f(s); }
  __syncthreads();
  if (t == 0) {
    float s = hb[0] * tw.nw6[0] + hb[1] * tw.nw6[1] + tw.nb6[0];
    float g0 = gelu_f(s * tw.gw0[0] + tw.gb0[0]);
    float g1 = gelu_f(s * tw.gw0[1] + tw.gb0[1]);
    outp[b] = g0 * tw.gw1[0] + g1 * tw.gw1[1] + tw.gb1[0];
  }
}

// ================= host =======================================================================
extern "C" void kernel_launch(void* const* d_in, const int* in_sizes, int n_in,
                              void* d_out, int out_size, void* d_ws, size_t ws_size,
                              hipStream_t stream) {
  const float* x_op = (const float*)d_in[0];
  const float* x_v  = (const float*)d_in[1];
  const int*   ei0  = (const int*)d_in[2];
  const int*   ei1  = (const int*)d_in[3];
  const float* Wk   = (const float*)d_in[4];
  const float* Wq   = (const float*)d_in[5];
  const float* Wv   = (const float*)d_in[6];
  const float* Wa   = (const float*)d_in[7];
  const float* bk   = (const float*)d_in[8];
  const float* bq   = (const float*)d_in[9];
  const float* bv   = (const float*)d_in[10];
  const float* ba   = (const float*)d_in[11];
  const float* skip = (const float*)d_in[12];
  const float* a_rel = (const float*)d_in[13];
  const float* m_rel = (const float*)d_in[14];
  const float* p_rel = (const float*)d_in[15];
  (void)in_sizes; (void)n_in; (void)out_size; (void)ws_size;

  char* wsp = (char*)d_ws;
  size_t off = 0;
  auto alloc = [&](size_t bytes) -> void* {
    void* p = wsp + off;
    off += (bytes + 255) & ~(size_t)255;
    return p;
  };
  float* P     = (float*)alloc((size_t)NN * PST * 4);
  float* xop   = (float*)alloc((size_t)NN * HID * 4);
  float* agg   = (float*)alloc((size_t)NN * HID * 4);
  float* CW    = (float*)alloc((size_t)16 * HID * HID * 4);
  float* CB    = (float*)alloc((size_t)16 * HID * 4);
  unsigned short* FW = (unsigned short*)alloc((size_t)24 * 32768 * 2);  // 1.57 MB frag weights
  float* xv    = (float*)alloc((size_t)NV * HID * 4);
  float* qv    = (float*)alloc((size_t)NV * HID * 4);
  float* outsv = (float*)alloc((size_t)NL * NV * HID * 4);
  float* part  = (float*)alloc((size_t)NV * 32 * 192 * 4);
  int* rowptr0 = (int*)alloc((size_t)(NN + 1) * 4);
  int* cur0    = (int*)alloc((size_t)NN * 4);
  int* col0    = (int*)alloc((size_t)E0E * 4);
  int* rowptr1 = (int*)alloc((size_t)(NV + 1) * 4);
  int* cur1    = (int*)alloc((size_t)NV * 4);
  int* col1    = (int*)alloc((size_t)NN * 4);

  k_setup<<<144, 256, 0, stream>>>(cur0, cur1, Wk, Wv, bk, bv, a_rel, m_rel, p_rel, CW, CB);
  k_frag<<<24, 256, 0, stream>>>(CW, Wq, Wa, FW);
  k_hist2<<<E0E / 1024 + NN / 1024, 256, 0, stream>>>(ei0 + E0E, ei1 + NN, cur0, cur1);
  k_scan2<<<2, 1024, 0, stream>>>(cur0, rowptr0, cur1, rowptr1);
  k_scat2<<<E0E / 1024 + NN / 1024, 256, 0, stream>>>(ei0, ei0 + E0E, cur0, col0,
                                                      ei1, ei1 + NN, cur1, col1);

  // layer-0 projection straight from inputs (MFMA), one slice per block
  k_mproj<<<dim3(NN / 64, 5), 256, 0, stream>>>(x_op, FW + (size_t)16 * 32768, FW, bq, CB, P);
  k_qv0<<<NV, 128, 0, stream>>>(x_v, Wq + (size_t)1 * HID * HID, bq + HID, qv);

  for (int l = 0; l < NL; ++l) {
    k_edges<<<NN / 4 + NV * 8, 256, 0, stream>>>(P, rowptr0, col0, agg, qv, rowptr1, col1, part);
    PArgs f;
    f.agg = agg;
    f.WaF_l = FW + (size_t)(20 + l) * 32768;
    f.ba_l0 = ba + (l * 2 + 0) * HID;
    f.skip_l0 = skip + l * 2 + 0;
    f.xold = (l == 0) ? x_op : xop;
    f.xop = xop;
    f.part = part;
    f.Wa_l1 = Wa + (size_t)(l * 2 + 1) * HID * HID;
    f.ba_l1 = ba + (l * 2 + 1) * HID;
    f.skip_l1 = skip + l * 2 + 1;
    f.xvold = (l == 0) ? x_v : xv;
    f.xv = xv;
    f.outsv_l = outsv + (size_t)l * NV * HID;
    f.qv = qv;
    int ln = (l + 1) & 3;
    f.Wq_n1 = Wq + (size_t)(ln * 2 + 1) * HID * HID;
    f.bq_n1 = bq + (ln * 2 + 1) * HID;
    f.do_qv = (l < NL - 1) ? 1 : 0;
    k_post<<<NN / 64 + NV, 256, 0, stream>>>(f);
    if (l < NL - 1) {
      k_mproj<<<dim3(NN / 64, 5), 256, 0, stream>>>(xop, FW + (size_t)(16 + ln) * 32768,
                                                    FW + (size_t)(ln * 4) * 32768,
                                                    bq + (ln * 2 + 0) * HID,
                                                    CB + ln * 4 * HID, P);
    }
  }

  TailW tw;
  tw.win  = (const float*)d_in[16]; tw.bin  = (const float*)d_in[17];
  tw.wout = (const float*)d_in[18]; tw.bout = (const float*)d_in[19];
  tw.nw0 = (const float*)d_in[20]; tw.nb0 = (const float*)d_in[21];
  tw.nw1 = (const float*)d_in[22]; tw.nb1 = (const float*)d_in[23];
  tw.nw2 = (const float*)d_in[24]; tw.nb2 = (const float*)d_in[25];
  tw.nw3 = (const float*)d_in[26]; tw.nb3 = (const float*)d_in[27];
  tw.nw4 = (const float*)d_in[28]; tw.nb4 = (const float*)d_in[29];
  tw.nw5 = (const float*)d_in[30]; tw.nb5 = (const float*)d_in[31];
  tw.nw6 = (const float*)d_in[32]; tw.nb6 = (const float*)d_in[33];
  tw.gw0 = (const float*)d_in[34]; tw.gb0 = (const float*)d_in[35];
  tw.gw1 = (const float*)d_in[36]; tw.gb1 = (const float*)d_in[37];
  k_final<<<NV, 128, 0, stream>>>(outsv, tw, (float*)d_out);
}